// Round 1
// baseline (626.004 us; speedup 1.0000x reference)
//
#include <hip/hip_runtime.h>

typedef unsigned int u32;
typedef unsigned short u16;
typedef __attribute__((ext_vector_type(8))) short short8;
typedef __attribute__((ext_vector_type(4))) float f32x4;

__device__ inline float bfu2f(u32 u) { return __builtin_bit_cast(float, u); }
__device__ inline u16 f2bf(float f) {
    u32 u = __builtin_bit_cast(u32, f);
    u32 r = (u + 0x7fffu + ((u >> 16) & 1u)) >> 16;  // RTNE
    return (u16)r;
}

// ---------- CSR build ----------
__global__ void k_count(const int* __restrict__ dst, int E, int* __restrict__ cnt) {
    int e = blockIdx.x * 256 + threadIdx.x;
    if (e < E) atomicAdd(&cnt[dst[e]], 1);
}

__global__ void k_dinv(const int* __restrict__ cnt, float* __restrict__ dinv, int N) {
    int i = blockIdx.x * 256 + threadIdx.x;
    if (i < N) dinv[i] = rsqrtf((float)(cnt[i] + 1));  // +1 self loop
}

__global__ void k_scan1(const int* __restrict__ cnt, int N, int* __restrict__ offs,
                        int* __restrict__ bsum) {
    __shared__ int wsum[4];
    int t = threadIdx.x, b = blockIdx.x;
    int base = b * 1024 + t * 4;
    int4 raw = *(const int4*)(cnt + base);  // ws padded; OOB lanes masked below
    int v0 = (base + 0 < N) ? raw.x : 0, v1 = (base + 1 < N) ? raw.y : 0;
    int v2 = (base + 2 < N) ? raw.z : 0, v3 = (base + 3 < N) ? raw.w : 0;
    int s = v0 + v1 + v2 + v3;
    int lane = t & 63, wv = t >> 6;
    int isc = s;
    for (int d = 1; d < 64; d <<= 1) { int o = __shfl_up(isc, d, 64); if (lane >= d) isc += o; }
    if (lane == 63) wsum[wv] = isc;
    __syncthreads();
    int woff = 0;
    for (int w = 0; w < wv; w++) woff += wsum[w];
    int run = woff + isc - s;
    if (base + 0 < N) offs[base + 0] = run; run += v0;
    if (base + 1 < N) offs[base + 1] = run; run += v1;
    if (base + 2 < N) offs[base + 2] = run; run += v2;
    if (base + 3 < N) offs[base + 3] = run;
    if (t == 255) bsum[b] = woff + isc;
}

__global__ void k_scan2(int* __restrict__ bsum, int NB, int* __restrict__ offs, int N) {
    __shared__ int wsum[4];
    int t = threadIdx.x;
    int v = (t < NB) ? bsum[t] : 0;
    int lane = t & 63, wv = t >> 6;
    int isc = v;
    for (int d = 1; d < 64; d <<= 1) { int o = __shfl_up(isc, d, 64); if (lane >= d) isc += o; }
    if (lane == 63) wsum[wv] = isc;
    __syncthreads();
    int woff = 0;
    for (int w = 0; w < wv; w++) woff += wsum[w];
    int incl = woff + isc;
    if (t < NB) bsum[t] = incl - v;  // exclusive
    if (t == 255) offs[N] = incl;    // total == E
}

__global__ void k_scan3(int* __restrict__ offs, const int* __restrict__ bsum, int N,
                        int* __restrict__ cursor) {
    int i = blockIdx.x * 256 + threadIdx.x;
    if (i < N) { offs[i] += bsum[i >> 10]; cursor[i] = 0; }
}

__global__ void k_scatter(const int* __restrict__ ei, int E, const int* __restrict__ offs,
                          int* __restrict__ cursor, int* __restrict__ csr) {
    int e = blockIdx.x * 256 + threadIdx.x;
    if (e < E) {
        int src = ei[e], dst = ei[E + e];
        int pos = atomicAdd(&cursor[dst], 1);
        csr[offs[dst] + pos] = src;
    }
}

// ---------- dtype converts ----------
__global__ void k_wtcvt(const float* __restrict__ W, u16* __restrict__ Wt, int K, int M) {
    int idx = blockIdx.x * 256 + threadIdx.x;  // W is [K][M] row-major -> Wt [M][K]
    if (idx < K * M) {
        int k = idx / M, m = idx - k * M;
        Wt[m * K + k] = f2bf(W[idx]);
    }
}

__global__ void k_xcvt(const float4* __restrict__ x, uint2* __restrict__ xb, int n4) {
    int i = blockIdx.x * 256 + threadIdx.x;
    if (i < n4) {
        float4 v = x[i];
        u32 lo = (u32)f2bf(v.x) | ((u32)f2bf(v.y) << 16);
        u32 hi = (u32)f2bf(v.z) | ((u32)f2bf(v.w) << 16);
        xb[i] = make_uint2(lo, hi);
    }
}

// ---------- GEMM: g = (x @ W) * dinv[row], bf16 out ----------
// A-operand = Wt tile (M=16 n's x K=32), B-operand = x tile (K=32 x 16 nodes)
// => D[n][node]: lane&15 = node, (lane>>4)*4+reg = n  -> 8B packed stores, dinv uniform per lane.
template <int M>
__global__ __launch_bounds__(256) void k_gemm(const u16* __restrict__ xin,
                                              const u16* __restrict__ wt,
                                              const float* __restrict__ dinv,
                                              u16* __restrict__ gout, int N) {
    constexpr int K = 128;
    constexpr int LDK = 136;  // +8 shorts pad: 4-bank shift/row -> conflict-free b128 reads
    __shared__ u16 lwt[M * LDK];
    int tid = threadIdx.x;
    const uint4* wsrc = (const uint4*)wt;
#pragma unroll
    for (int c = tid; c < M * K / 8; c += 256) {
        int row = c >> 4, kc = c & 15;
        *(uint4*)&lwt[row * LDK + kc * 8] = wsrc[c];
    }
    __syncthreads();
    int lane = tid & 63, wv = tid >> 6;
    int node = blockIdx.x * 64 + wv * 16 + (lane & 15);
    int nodec = min(node, N - 1);
    int kr = (lane >> 4) * 8;
    f32x4 acc[M / 16];
#pragma unroll
    for (int t = 0; t < M / 16; t++) acc[t] = (f32x4){0.f, 0.f, 0.f, 0.f};
    const short8* xrow = (const short8*)(xin + (size_t)nodec * K);
#pragma unroll
    for (int ks = 0; ks < 4; ks++) {
        short8 bfr = xrow[ks * 4 + (kr >> 3)];
#pragma unroll
        for (int t = 0; t < M / 16; t++) {
            short8 afr = *(const short8*)&lwt[(t * 16 + (lane & 15)) * LDK + ks * 32 + kr];
            acc[t] = __builtin_amdgcn_mfma_f32_16x16x32_bf16(afr, bfr, acc[t], 0, 0, 0);
        }
    }
    if (node < N) {
        float dv = dinv[node];
        int r0 = (lane >> 4) * 4;
#pragma unroll
        for (int t = 0; t < M / 16; t++) {
            u32 lo = (u32)f2bf(acc[t][0] * dv) | ((u32)f2bf(acc[t][1] * dv) << 16);
            u32 hi = (u32)f2bf(acc[t][2] * dv) | ((u32)f2bf(acc[t][3] * dv) << 16);
            *(uint2*)&gout[(size_t)node * M + t * 16 + r0] = make_uint2(lo, hi);
        }
    }
}

// ---------- aggregation: out[i] = relu(dinv[i]*(g[i] + sum g[src]) + b), bf16 out ----------
__global__ __launch_bounds__(256) void k_agg128(const u16* __restrict__ g,
                                                const int* __restrict__ offs,
                                                const int* __restrict__ csr,
                                                const float* __restrict__ dinv,
                                                const float* __restrict__ bias,
                                                u16* __restrict__ hout, int N) {
    int wid = (blockIdx.x * 256 + threadIdx.x) >> 6;  // one wave per node
    if (wid >= N) return;
    int lane = threadIdx.x & 63;
    int s = offs[wid], e = offs[wid + 1];
    u32 p = *(const u32*)(g + (size_t)wid * 128 + lane * 2);  // self loop
    float a0 = bfu2f(p << 16), a1 = bfu2f(p & 0xffff0000u);
    int j = s;
    for (; j + 2 <= e; j += 2) {  // 2 outstanding gathers
        int s0 = csr[j], s1 = csr[j + 1];
        u32 q0 = *(const u32*)(g + (size_t)s0 * 128 + lane * 2);
        u32 q1 = *(const u32*)(g + (size_t)s1 * 128 + lane * 2);
        a0 += bfu2f(q0 << 16); a1 += bfu2f(q0 & 0xffff0000u);
        a0 += bfu2f(q1 << 16); a1 += bfu2f(q1 & 0xffff0000u);
    }
    if (j < e) {
        int s0 = csr[j];
        u32 q0 = *(const u32*)(g + (size_t)s0 * 128 + lane * 2);
        a0 += bfu2f(q0 << 16); a1 += bfu2f(q0 & 0xffff0000u);
    }
    float dv = dinv[wid];
    float2 bb = *(const float2*)(bias + lane * 2);
    float v0 = fmaxf(fmaf(a0, dv, bb.x), 0.f);
    float v1 = fmaxf(fmaf(a1, dv, bb.y), 0.f);
    *(u32*)(hout + (size_t)wid * 128 + lane * 2) = (u32)f2bf(v0) | ((u32)f2bf(v1) << 16);
}

// ---------- layer-3 aggregation + log_softmax (F=64, fp32 out) ----------
__global__ __launch_bounds__(256) void k_agg64(const u16* __restrict__ g,
                                               const int* __restrict__ offs,
                                               const int* __restrict__ csr,
                                               const float* __restrict__ dinv,
                                               const float* __restrict__ bias,
                                               float* __restrict__ out, int N) {
    int wid = (blockIdx.x * 256 + threadIdx.x) >> 6;
    if (wid >= N) return;
    int lane = threadIdx.x & 63;
    int s = offs[wid], e = offs[wid + 1];
    float a = bfu2f(((u32)g[(size_t)wid * 64 + lane]) << 16);
    int j = s;
    for (; j + 2 <= e; j += 2) {
        int s0 = csr[j], s1 = csr[j + 1];
        u32 q0 = g[(size_t)s0 * 64 + lane];
        u32 q1 = g[(size_t)s1 * 64 + lane];
        a += bfu2f(q0 << 16);
        a += bfu2f(q1 << 16);
    }
    if (j < e) a += bfu2f(((u32)g[(size_t)csr[j] * 64 + lane]) << 16);
    float v = fmaf(a, dinv[wid], bias[lane]);
    float m = v;
#pragma unroll
    for (int d = 32; d >= 1; d >>= 1) m = fmaxf(m, __shfl_xor(m, d, 64));
    float ex = __expf(v - m);
    float ssum = ex;
#pragma unroll
    for (int d = 32; d >= 1; d >>= 1) ssum += __shfl_xor(ssum, d, 64);
    out[(size_t)wid * 64 + lane] = v - m - __logf(ssum);
}

extern "C" void kernel_launch(void* const* d_in, const int* in_sizes, int n_in,
                              void* d_out, int out_size, void* d_ws, size_t ws_size,
                              hipStream_t stream) {
    const float* x  = (const float*)d_in[0];
    const int*   ei = (const int*)d_in[1];
    const float* W1 = (const float*)d_in[2];
    const float* b1 = (const float*)d_in[3];
    const float* W2 = (const float*)d_in[4];
    const float* b2 = (const float*)d_in[5];
    const float* W3 = (const float*)d_in[6];
    const float* b3 = (const float*)d_in[7];
    const int N = in_sizes[0] / 128;
    const int E = in_sizes[1] / 2;

    char* ws = (char*)d_ws;
    size_t o = 0;
    auto alloc = [&](size_t bytes) -> char* {
        char* p = ws + o;
        o += (bytes + 255) & ~(size_t)255;
        return p;
    };
    int*   cnt  = (int*)alloc((size_t)N * 4);        // reused as scatter cursor
    float* dinv = (float*)alloc((size_t)N * 4);
    int*   offs = (int*)alloc((size_t)(N + 1) * 4);
    int*   bsum = (int*)alloc(4096);
    int*   csr  = (int*)alloc((size_t)E * 4);
    u16*   wt1  = (u16*)alloc(128 * 128 * 2);
    u16*   wt2  = (u16*)alloc(128 * 128 * 2);
    u16*   wt3  = (u16*)alloc(64 * 128 * 2);
    u16*   bufA = (u16*)alloc((size_t)N * 128 * 2);
    u16*   bufB = (u16*)alloc((size_t)N * 128 * 2);
    u16*   bufC = (u16*)alloc((size_t)N * 128 * 2);
    float* outp = (float*)d_out;

    hipMemsetAsync(cnt, 0, (size_t)N * 4, stream);
    int gE = (E + 255) / 256;
    int gN = (N + 255) / 256;
    int NB = (N + 1023) / 1024;
    k_count<<<gE, 256, 0, stream>>>(ei + E, E, cnt);
    k_dinv<<<gN, 256, 0, stream>>>(cnt, dinv, N);
    k_scan1<<<NB, 256, 0, stream>>>(cnt, N, offs, bsum);
    k_scan2<<<1, 256, 0, stream>>>(bsum, NB, offs, N);
    k_scan3<<<gN, 256, 0, stream>>>(offs, bsum, N, cnt);
    k_scatter<<<gE, 256, 0, stream>>>(ei, E, offs, cnt, csr);

    k_wtcvt<<<(128 * 128 + 255) / 256, 256, 0, stream>>>(W1, wt1, 128, 128);
    k_wtcvt<<<(128 * 128 + 255) / 256, 256, 0, stream>>>(W2, wt2, 128, 128);
    k_wtcvt<<<(128 * 64 + 255) / 256, 256, 0, stream>>>(W3, wt3, 128, 64);
    int n4 = N * 128 / 4;
    k_xcvt<<<(n4 + 255) / 256, 256, 0, stream>>>((const float4*)x, (uint2*)bufA, n4);

    int gG = (N + 63) / 64;                       // GEMM: 64 nodes/block
    int gA = (int)(((size_t)N * 64 + 255) / 256); // agg: 1 wave/node

    k_gemm<128><<<gG, 256, 0, stream>>>(bufA, wt1, dinv, bufB, N);
    k_agg128<<<gA, 256, 0, stream>>>(bufB, offs, csr, dinv, b1, bufC, N);
    k_gemm<128><<<gG, 256, 0, stream>>>(bufC, wt2, dinv, bufA, N);
    k_agg128<<<gA, 256, 0, stream>>>(bufA, offs, csr, dinv, b2, bufB, N);
    k_gemm<64><<<gG, 256, 0, stream>>>(bufB, wt3, dinv, bufC, N);
    k_agg64<<<gA, 256, 0, stream>>>(bufC, offs, csr, dinv, b3, outp, N);
}

// Round 2
// 474.108 us; speedup vs baseline: 1.3204x; 1.3204x over previous
//
#include <hip/hip_runtime.h>

typedef unsigned int u32;
typedef unsigned short u16;
typedef __attribute__((ext_vector_type(8))) short short8;
typedef __attribute__((ext_vector_type(4))) float f32x4;

__device__ inline float bfu2f(u32 u) { return __builtin_bit_cast(float, u); }
__device__ inline u16 f2bf(float f) {
    u32 u = __builtin_bit_cast(u32, f);
    u32 r = (u + 0x7fffu + ((u >> 16) & 1u)) >> 16;  // RTNE
    return (u16)r;
}

// ---------- CSR build ----------
// count in-degree AND capture each edge's slot within its dst's list.
__global__ void k_count(const int* __restrict__ ei, int E, int* __restrict__ cnt,
                        int* __restrict__ pos) {
    int e = blockIdx.x * 256 + threadIdx.x;
    if (e < E) pos[e] = atomicAdd(&cnt[ei[E + e]], 1);
}

__global__ void k_scan1(const int* __restrict__ cnt, int N, int* __restrict__ offs,
                        int* __restrict__ bsum, float* __restrict__ dinv) {
    __shared__ int wsum[4];
    int t = threadIdx.x, b = blockIdx.x;
    int base = b * 1024 + t * 4;
    int4 raw = *(const int4*)(cnt + base);  // ws padded; OOB lanes masked below
    int v0 = (base + 0 < N) ? raw.x : 0, v1 = (base + 1 < N) ? raw.y : 0;
    int v2 = (base + 2 < N) ? raw.z : 0, v3 = (base + 3 < N) ? raw.w : 0;
    int s = v0 + v1 + v2 + v3;
    int lane = t & 63, wv = t >> 6;
    int isc = s;
    for (int d = 1; d < 64; d <<= 1) { int o = __shfl_up(isc, d, 64); if (lane >= d) isc += o; }
    if (lane == 63) wsum[wv] = isc;
    __syncthreads();
    int woff = 0;
    for (int w = 0; w < wv; w++) woff += wsum[w];
    int run = woff + isc - s;
    if (base + 0 < N) { offs[base + 0] = run; dinv[base + 0] = rsqrtf((float)(v0 + 1)); } run += v0;
    if (base + 1 < N) { offs[base + 1] = run; dinv[base + 1] = rsqrtf((float)(v1 + 1)); } run += v1;
    if (base + 2 < N) { offs[base + 2] = run; dinv[base + 2] = rsqrtf((float)(v2 + 1)); } run += v2;
    if (base + 3 < N) { offs[base + 3] = run; dinv[base + 3] = rsqrtf((float)(v3 + 1)); }
    if (t == 255) bsum[b] = woff + isc;
}

__global__ void k_scan2(int* __restrict__ bsum, int NB, int* __restrict__ offs, int N) {
    __shared__ int wsum[4];
    int t = threadIdx.x;
    int v = (t < NB) ? bsum[t] : 0;
    int lane = t & 63, wv = t >> 6;
    int isc = v;
    for (int d = 1; d < 64; d <<= 1) { int o = __shfl_up(isc, d, 64); if (lane >= d) isc += o; }
    if (lane == 63) wsum[wv] = isc;
    __syncthreads();
    int woff = 0;
    for (int w = 0; w < wv; w++) woff += wsum[w];
    int incl = woff + isc;
    if (t < NB) bsum[t] = incl - v;  // exclusive
    if (t == 255) offs[N] = incl;    // total == E
}

__global__ void k_scan3(int* __restrict__ offs, const int* __restrict__ bsum, int N) {
    int i = blockIdx.x * 256 + threadIdx.x;
    if (i < N) offs[i] += bsum[i >> 10];
}

// atomic-free placement, binned by dst range so the csr write window (~1.6MB)
// stays L2-resident -> 64B lines absorb ~16 entry-writes before eviction.
__global__ void k_place(const int* __restrict__ ei, const int* __restrict__ pos, int E,
                        const int* __restrict__ offs, int* __restrict__ csr,
                        int lo, int hi) {
    int e = blockIdx.x * 256 + threadIdx.x;
    if (e < E) {
        int dst = ei[E + e];
        if (dst >= lo && dst < hi) csr[offs[dst] + pos[e]] = ei[e];
    }
}

// ---------- dtype converts ----------
__global__ void k_wtcvt(const float* __restrict__ W, u16* __restrict__ Wt, int K, int M) {
    int idx = blockIdx.x * 256 + threadIdx.x;  // W is [K][M] row-major -> Wt [M][K]
    if (idx < K * M) {
        int k = idx / M, m = idx - k * M;
        Wt[m * K + k] = f2bf(W[idx]);
    }
}

__global__ void k_xcvt(const float4* __restrict__ x, uint2* __restrict__ xb, int n4) {
    int i = blockIdx.x * 256 + threadIdx.x;
    if (i < n4) {
        float4 v = x[i];
        u32 lo = (u32)f2bf(v.x) | ((u32)f2bf(v.y) << 16);
        u32 hi = (u32)f2bf(v.z) | ((u32)f2bf(v.w) << 16);
        xb[i] = make_uint2(lo, hi);
    }
}

// ---------- GEMM: g = (x @ W) * dinv[row], bf16 out ----------
// A-operand = Wt tile (M=16 n's x K=32), B-operand = x tile (K=32 x 16 nodes)
// => D[n][node]: lane&15 = node, (lane>>4)*4+reg = n  -> 8B packed stores, dinv uniform per lane.
template <int M>
__global__ __launch_bounds__(256) void k_gemm(const u16* __restrict__ xin,
                                              const u16* __restrict__ wt,
                                              const float* __restrict__ dinv,
                                              u16* __restrict__ gout, int N) {
    constexpr int K = 128;
    constexpr int LDK = 136;  // +8 shorts pad: conflict-free b128 reads
    __shared__ u16 lwt[M * LDK];
    int tid = threadIdx.x;
    const uint4* wsrc = (const uint4*)wt;
#pragma unroll
    for (int c = tid; c < M * K / 8; c += 256) {
        int row = c >> 4, kc = c & 15;
        *(uint4*)&lwt[row * LDK + kc * 8] = wsrc[c];
    }
    __syncthreads();
    int lane = tid & 63, wv = tid >> 6;
    int node = blockIdx.x * 64 + wv * 16 + (lane & 15);
    int nodec = min(node, N - 1);
    int kr = (lane >> 4) * 8;
    f32x4 acc[M / 16];
#pragma unroll
    for (int t = 0; t < M / 16; t++) acc[t] = (f32x4){0.f, 0.f, 0.f, 0.f};
    const short8* xrow = (const short8*)(xin + (size_t)nodec * K);
#pragma unroll
    for (int ks = 0; ks < 4; ks++) {
        short8 bfr = xrow[ks * 4 + (kr >> 3)];
#pragma unroll
        for (int t = 0; t < M / 16; t++) {
            short8 afr = *(const short8*)&lwt[(t * 16 + (lane & 15)) * LDK + ks * 32 + kr];
            acc[t] = __builtin_amdgcn_mfma_f32_16x16x32_bf16(afr, bfr, acc[t], 0, 0, 0);
        }
    }
    if (node < N) {
        float dv = dinv[node];
        int r0 = (lane >> 4) * 4;
#pragma unroll
        for (int t = 0; t < M / 16; t++) {
            u32 lo = (u32)f2bf(acc[t][0] * dv) | ((u32)f2bf(acc[t][1] * dv) << 16);
            u32 hi = (u32)f2bf(acc[t][2] * dv) | ((u32)f2bf(acc[t][3] * dv) << 16);
            *(uint2*)&gout[(size_t)node * M + t * 16 + r0] = make_uint2(lo, hi);
        }
    }
}

// ---------- aggregation: out[i] = relu(dinv[i]*(g[i] + sum g[src]) + b), bf16 out ----------
__global__ __launch_bounds__(256) void k_agg128(const u16* __restrict__ g,
                                                const int* __restrict__ offs,
                                                const int* __restrict__ csr,
                                                const float* __restrict__ dinv,
                                                const float* __restrict__ bias,
                                                u16* __restrict__ hout, int N) {
    int wid = (blockIdx.x * 256 + threadIdx.x) >> 6;  // one wave per node
    if (wid >= N) return;
    int lane = threadIdx.x & 63;
    int s = offs[wid], e = offs[wid + 1];
    u32 p = *(const u32*)(g + (size_t)wid * 128 + lane * 2);  // self loop
    float a0 = bfu2f(p << 16), a1 = bfu2f(p & 0xffff0000u);
    int j = s;
    for (; j + 4 <= e; j += 4) {  // 4 outstanding gathers
        int s0 = csr[j], s1 = csr[j + 1], s2 = csr[j + 2], s3 = csr[j + 3];
        u32 q0 = *(const u32*)(g + (size_t)s0 * 128 + lane * 2);
        u32 q1 = *(const u32*)(g + (size_t)s1 * 128 + lane * 2);
        u32 q2 = *(const u32*)(g + (size_t)s2 * 128 + lane * 2);
        u32 q3 = *(const u32*)(g + (size_t)s3 * 128 + lane * 2);
        a0 += bfu2f(q0 << 16); a1 += bfu2f(q0 & 0xffff0000u);
        a0 += bfu2f(q1 << 16); a1 += bfu2f(q1 & 0xffff0000u);
        a0 += bfu2f(q2 << 16); a1 += bfu2f(q2 & 0xffff0000u);
        a0 += bfu2f(q3 << 16); a1 += bfu2f(q3 & 0xffff0000u);
    }
    for (; j < e; j++) {
        u32 q0 = *(const u32*)(g + (size_t)csr[j] * 128 + lane * 2);
        a0 += bfu2f(q0 << 16); a1 += bfu2f(q0 & 0xffff0000u);
    }
    float dv = dinv[wid];
    float2 bb = *(const float2*)(bias + lane * 2);
    float v0 = fmaxf(fmaf(a0, dv, bb.x), 0.f);
    float v1 = fmaxf(fmaf(a1, dv, bb.y), 0.f);
    *(u32*)(hout + (size_t)wid * 128 + lane * 2) = (u32)f2bf(v0) | ((u32)f2bf(v1) << 16);
}

// ---------- layer-3 aggregation + log_softmax (F=64, fp32 out) ----------
__global__ __launch_bounds__(256) void k_agg64(const u16* __restrict__ g,
                                               const int* __restrict__ offs,
                                               const int* __restrict__ csr,
                                               const float* __restrict__ dinv,
                                               const float* __restrict__ bias,
                                               float* __restrict__ out, int N) {
    int wid = (blockIdx.x * 256 + threadIdx.x) >> 6;
    if (wid >= N) return;
    int lane = threadIdx.x & 63;
    int s = offs[wid], e = offs[wid + 1];
    float a = bfu2f(((u32)g[(size_t)wid * 64 + lane]) << 16);
    int j = s;
    for (; j + 4 <= e; j += 4) {
        int s0 = csr[j], s1 = csr[j + 1], s2 = csr[j + 2], s3 = csr[j + 3];
        u32 q0 = g[(size_t)s0 * 64 + lane];
        u32 q1 = g[(size_t)s1 * 64 + lane];
        u32 q2 = g[(size_t)s2 * 64 + lane];
        u32 q3 = g[(size_t)s3 * 64 + lane];
        a += bfu2f(q0 << 16) + bfu2f(q1 << 16) + bfu2f(q2 << 16) + bfu2f(q3 << 16);
    }
    for (; j < e; j++) a += bfu2f(((u32)g[(size_t)csr[j] * 64 + lane]) << 16);
    float v = fmaf(a, dinv[wid], bias[lane]);
    float m = v;
#pragma unroll
    for (int d = 32; d >= 1; d >>= 1) m = fmaxf(m, __shfl_xor(m, d, 64));
    float ex = __expf(v - m);
    float ssum = ex;
#pragma unroll
    for (int d = 32; d >= 1; d >>= 1) ssum += __shfl_xor(ssum, d, 64);
    out[(size_t)wid * 64 + lane] = v - m - __logf(ssum);
}

extern "C" void kernel_launch(void* const* d_in, const int* in_sizes, int n_in,
                              void* d_out, int out_size, void* d_ws, size_t ws_size,
                              hipStream_t stream) {
    const float* x  = (const float*)d_in[0];
    const int*   ei = (const int*)d_in[1];
    const float* W1 = (const float*)d_in[2];
    const float* b1 = (const float*)d_in[3];
    const float* W2 = (const float*)d_in[4];
    const float* b2 = (const float*)d_in[5];
    const float* W3 = (const float*)d_in[6];
    const float* b3 = (const float*)d_in[7];
    const int N = in_sizes[0] / 128;
    const int E = in_sizes[1] / 2;

    char* ws = (char*)d_ws;
    size_t o = 0;
    auto alloc = [&](size_t bytes) -> char* {
        char* p = ws + o;
        o += (bytes + 255) & ~(size_t)255;
        return p;
    };
    int*   cnt  = (int*)alloc((size_t)N * 4);
    float* dinv = (float*)alloc((size_t)N * 4);
    int*   offs = (int*)alloc((size_t)(N + 1) * 4);
    int*   bsum = (int*)alloc(4096);
    int*   csr  = (int*)alloc((size_t)E * 4);
    u16*   wt1  = (u16*)alloc(128 * 128 * 2);
    u16*   wt2  = (u16*)alloc(128 * 128 * 2);
    u16*   wt3  = (u16*)alloc(64 * 128 * 2);
    u16*   bufA = (u16*)alloc((size_t)N * 128 * 2);
    u16*   bufB = (u16*)alloc((size_t)N * 128 * 2);
    u16*   bufC = (u16*)alloc((size_t)N * 128 * 2);
    int*   pos  = (int*)bufC;  // lifetime-disjoint alias: pos dead before first bufC use
    float* outp = (float*)d_out;

    hipMemsetAsync(cnt, 0, (size_t)N * 4, stream);
    int gE = (E + 255) / 256;
    int NB = (N + 1023) / 1024;
    k_count<<<gE, 256, 0, stream>>>(ei, E, cnt, pos);
    k_scan1<<<NB, 256, 0, stream>>>(cnt, N, offs, bsum, dinv);
    k_scan2<<<1, 256, 0, stream>>>(bsum, NB, offs, N);
    k_scan3<<<(N + 255) / 256, 256, 0, stream>>>(offs, bsum, N);
    constexpr int KBIN = 4;
    for (int p = 0; p < KBIN; p++) {
        int lo = (int)((long long)N * p / KBIN);
        int hi = (int)((long long)N * (p + 1) / KBIN);
        k_place<<<gE, 256, 0, stream>>>(ei, pos, E, offs, csr, lo, hi);
    }

    k_wtcvt<<<(128 * 128 + 255) / 256, 256, 0, stream>>>(W1, wt1, 128, 128);
    k_wtcvt<<<(128 * 128 + 255) / 256, 256, 0, stream>>>(W2, wt2, 128, 128);
    k_wtcvt<<<(128 * 64 + 255) / 256, 256, 0, stream>>>(W3, wt3, 128, 64);
    int n4 = N * 128 / 4;
    k_xcvt<<<(n4 + 255) / 256, 256, 0, stream>>>((const float4*)x, (uint2*)bufA, n4);

    int gG = (N + 63) / 64;                       // GEMM: 64 nodes/block
    int gA = (int)(((size_t)N * 64 + 255) / 256); // agg: 1 wave/node

    k_gemm<128><<<gG, 256, 0, stream>>>(bufA, wt1, dinv, bufB, N);
    k_agg128<<<gA, 256, 0, stream>>>(bufB, offs, csr, dinv, b1, bufC, N);
    k_gemm<128><<<gG, 256, 0, stream>>>(bufC, wt2, dinv, bufA, N);
    k_agg128<<<gA, 256, 0, stream>>>(bufA, offs, csr, dinv, b2, bufB, N);
    k_gemm<64><<<gG, 256, 0, stream>>>(bufB, wt3, dinv, bufC, N);
    k_agg64<<<gA, 256, 0, stream>>>(bufC, offs, csr, dinv, b3, outp, N);
}

// Round 3
// 465.109 us; speedup vs baseline: 1.3459x; 1.0193x over previous
//
#include <hip/hip_runtime.h>

typedef unsigned int u32;
typedef unsigned short u16;
typedef unsigned char u8;
typedef __attribute__((ext_vector_type(8))) short short8;
typedef __attribute__((ext_vector_type(4))) float f32x4;
typedef __attribute__((ext_vector_type(2))) float f32x2;

__device__ inline float bfu2f(u32 u) { return __builtin_bit_cast(float, u); }
__device__ inline u16 f2bf(float f) {
    u32 u = __builtin_bit_cast(u32, f);
    u32 r = (u + 0x7fffu + ((u >> 16) & 1u)) >> 16;  // RTNE
    return (u16)r;
}

// ---------- CSR build ----------
__global__ void k_count(const int* __restrict__ ei, int E, int* __restrict__ cnt,
                        int* __restrict__ pos) {
    int e = blockIdx.x * 256 + threadIdx.x;
    if (e < E) pos[e] = atomicAdd(&cnt[ei[E + e]], 1);
}

__global__ void k_scan1(const int* __restrict__ cnt, int N, int* __restrict__ offs,
                        int* __restrict__ bsum, float* __restrict__ dinv) {
    __shared__ int wsum[4];
    int t = threadIdx.x, b = blockIdx.x;
    int base = b * 1024 + t * 4;
    int4 raw = *(const int4*)(cnt + base);
    int v0 = (base + 0 < N) ? raw.x : 0, v1 = (base + 1 < N) ? raw.y : 0;
    int v2 = (base + 2 < N) ? raw.z : 0, v3 = (base + 3 < N) ? raw.w : 0;
    int s = v0 + v1 + v2 + v3;
    int lane = t & 63, wv = t >> 6;
    int isc = s;
    for (int d = 1; d < 64; d <<= 1) { int o = __shfl_up(isc, d, 64); if (lane >= d) isc += o; }
    if (lane == 63) wsum[wv] = isc;
    __syncthreads();
    int woff = 0;
    for (int w = 0; w < wv; w++) woff += wsum[w];
    int run = woff + isc - s;
    if (base + 0 < N) { offs[base + 0] = run; dinv[base + 0] = rsqrtf((float)(v0 + 1)); } run += v0;
    if (base + 1 < N) { offs[base + 1] = run; dinv[base + 1] = rsqrtf((float)(v1 + 1)); } run += v1;
    if (base + 2 < N) { offs[base + 2] = run; dinv[base + 2] = rsqrtf((float)(v2 + 1)); } run += v2;
    if (base + 3 < N) { offs[base + 3] = run; dinv[base + 3] = rsqrtf((float)(v3 + 1)); }
    if (t == 255) bsum[b] = woff + isc;
}

__global__ void k_scan2(int* __restrict__ bsum, int NB, int* __restrict__ offs, int N) {
    __shared__ int wsum[4];
    int t = threadIdx.x;
    int v = (t < NB) ? bsum[t] : 0;
    int lane = t & 63, wv = t >> 6;
    int isc = v;
    for (int d = 1; d < 64; d <<= 1) { int o = __shfl_up(isc, d, 64); if (lane >= d) isc += o; }
    if (lane == 63) wsum[wv] = isc;
    __syncthreads();
    int woff = 0;
    for (int w = 0; w < wv; w++) woff += wsum[w];
    int incl = woff + isc;
    if (t < NB) bsum[t] = incl - v;
    if (t == 255) offs[N] = incl;
}

__global__ void k_scan3(int* __restrict__ offs, const int* __restrict__ bsum, int N) {
    int i = blockIdx.x * 256 + threadIdx.x;
    if (i < N) offs[i] += bsum[i >> 10];
}

// atomic-free placement, dst-binned so the csr write window stays L2-resident.
__global__ void k_place(const int* __restrict__ ei, const int* __restrict__ pos, int E,
                        const int* __restrict__ offs, int* __restrict__ csr,
                        int lo, int hi) {
    int e = blockIdx.x * 256 + threadIdx.x;
    if (e < E) {
        int dst = ei[E + e];
        if (dst >= lo && dst < hi) csr[offs[dst] + pos[e]] = ei[e];
    }
}

// ---------- fused weight converts (W[K][M] row-major -> Wt[M][K] bf16) ----------
__global__ void k_wtall(const float* __restrict__ W1, const float* __restrict__ W2,
                        const float* __restrict__ W3, u16* __restrict__ wt1,
                        u16* __restrict__ wt2, u16* __restrict__ wt3) {
    int idx = blockIdx.x * 256 + threadIdx.x;
    if (idx < 16384) {
        int k = idx >> 7, m = idx & 127;
        wt1[m * 128 + k] = f2bf(W1[idx]);
    } else if (idx < 32768) {
        int i = idx - 16384, k = i >> 7, m = i & 127;
        wt2[m * 128 + k] = f2bf(W2[i]);
    } else if (idx < 40960) {
        int i = idx - 32768, k = i >> 6, m = i & 63;
        wt3[m * 128 + k] = f2bf(W3[i]);
    }
}

// ---------- GEMM: g = (x @ W) * dinv[row]; writes bf16 (self) + fp8x16 (gather) ----------
// A = Wt tile (16 feats x K=32), B = x tile (K=32 x 16 nodes)
// D[feat][node]: lane&15 = node, (lane>>4)*4+reg = feat.
template <int M, bool F32IN>
__global__ __launch_bounds__(256) void k_gemm(const void* __restrict__ xin,
                                              const u16* __restrict__ wt,
                                              const float* __restrict__ dinv,
                                              u16* __restrict__ g16,
                                              u8* __restrict__ g8, int N) {
    constexpr int K = 128;
    constexpr int LDK = 136;  // +8 shorts pad: conflict-free b128 reads
    __shared__ u16 lwt[M * LDK];
    int tid = threadIdx.x;
    const uint4* wsrc = (const uint4*)wt;
#pragma unroll
    for (int c = tid; c < M * K / 8; c += 256) {
        int row = c >> 4, kc = c & 15;
        *(uint4*)&lwt[row * LDK + kc * 8] = wsrc[c];
    }
    __syncthreads();
    int lane = tid & 63, wv = tid >> 6;
    int node = blockIdx.x * 64 + wv * 16 + (lane & 15);
    int nodec = min(node, N - 1);
    int kr = (lane >> 4) * 8;
    f32x4 acc[M / 16];
#pragma unroll
    for (int t = 0; t < M / 16; t++) acc[t] = (f32x4){0.f, 0.f, 0.f, 0.f};
#pragma unroll
    for (int ks = 0; ks < 4; ks++) {
        short8 bfr;
        if (F32IN) {
            const float* xr = (const float*)xin + (size_t)nodec * K + ks * 32 + kr;
            float4 fa = *(const float4*)xr;
            float4 fb = *(const float4*)(xr + 4);
            bfr = (short8){(short)f2bf(fa.x), (short)f2bf(fa.y), (short)f2bf(fa.z),
                           (short)f2bf(fa.w), (short)f2bf(fb.x), (short)f2bf(fb.y),
                           (short)f2bf(fb.z), (short)f2bf(fb.w)};
        } else {
            bfr = *(const short8*)((const u16*)xin + (size_t)nodec * K + ks * 32 + kr);
        }
#pragma unroll
        for (int t = 0; t < M / 16; t++) {
            short8 afr = *(const short8*)&lwt[(t * 16 + (lane & 15)) * LDK + ks * 32 + kr];
            acc[t] = __builtin_amdgcn_mfma_f32_16x16x32_bf16(afr, bfr, acc[t], 0, 0, 0);
        }
    }
    if (node < N) {
        float dv = dinv[node];
        float dv16 = dv * 16.0f;
        int r0 = (lane >> 4) * 4;
#pragma unroll
        for (int t = 0; t < M / 16; t++) {
            float v0 = acc[t][0] * dv, v1 = acc[t][1] * dv;
            float v2 = acc[t][2] * dv, v3 = acc[t][3] * dv;
            u32 lo = (u32)f2bf(v0) | ((u32)f2bf(v1) << 16);
            u32 hi = (u32)f2bf(v2) | ((u32)f2bf(v3) << 16);
            *(uint2*)&g16[(size_t)node * M + t * 16 + r0] = make_uint2(lo, hi);
            u32 w = __builtin_amdgcn_cvt_pk_fp8_f32(acc[t][0] * dv16, acc[t][1] * dv16, 0, false);
            w = __builtin_amdgcn_cvt_pk_fp8_f32(acc[t][2] * dv16, acc[t][3] * dv16, w, true);
            *(u32*)(g8 + (size_t)node * M + t * 16 + r0) = w;
        }
    }
}

// ---------- aggregation: out[i] = relu(dinv[i]*(g16[i] + sum fp8 g8[src]/16) + b) ----------
__global__ __launch_bounds__(256) void k_agg128(const u8* __restrict__ g8,
                                                const u16* __restrict__ g16,
                                                const int* __restrict__ offs,
                                                const int* __restrict__ csr,
                                                const float* __restrict__ dinv,
                                                const float* __restrict__ bias,
                                                u16* __restrict__ hout, int N) {
    int wid = (blockIdx.x * 256 + threadIdx.x) >> 6;  // one wave per node
    if (wid >= N) return;
    int lane = threadIdx.x & 63;
    int s = offs[wid], e = offs[wid + 1];
    u32 p = *(const u32*)(g16 + (size_t)wid * 128 + lane * 2);  // self loop, bf16
    float self0 = bfu2f(p << 16), self1 = bfu2f(p & 0xffff0000u);
    float a0 = 0.f, a1 = 0.f;
    int j = s;
    for (; j + 4 <= e; j += 4) {  // 4 outstanding gathers
        int s0 = csr[j], s1 = csr[j + 1], s2 = csr[j + 2], s3 = csr[j + 3];
        u16 q0 = *(const u16*)(g8 + (size_t)s0 * 128 + lane * 2);
        u16 q1 = *(const u16*)(g8 + (size_t)s1 * 128 + lane * 2);
        u16 q2 = *(const u16*)(g8 + (size_t)s2 * 128 + lane * 2);
        u16 q3 = *(const u16*)(g8 + (size_t)s3 * 128 + lane * 2);
        f32x2 d0 = __builtin_amdgcn_cvt_pk_f32_fp8((int)q0, false);
        f32x2 d1 = __builtin_amdgcn_cvt_pk_f32_fp8((int)q1, false);
        f32x2 d2 = __builtin_amdgcn_cvt_pk_f32_fp8((int)q2, false);
        f32x2 d3 = __builtin_amdgcn_cvt_pk_f32_fp8((int)q3, false);
        a0 += d0.x + d1.x + d2.x + d3.x;
        a1 += d0.y + d1.y + d2.y + d3.y;
    }
    for (; j < e; j++) {
        u16 q0 = *(const u16*)(g8 + (size_t)csr[j] * 128 + lane * 2);
        f32x2 d0 = __builtin_amdgcn_cvt_pk_f32_fp8((int)q0, false);
        a0 += d0.x; a1 += d0.y;
    }
    float dv = dinv[wid];
    float dv16 = dv * 0.0625f;
    float2 bb = *(const float2*)(bias + lane * 2);
    float v0 = fmaxf(fmaf(a0, dv16, fmaf(self0, dv, bb.x)), 0.f);
    float v1 = fmaxf(fmaf(a1, dv16, fmaf(self1, dv, bb.y)), 0.f);
    *(u32*)&hout[(size_t)wid * 128 + lane * 2] = (u32)f2bf(v0) | ((u32)f2bf(v1) << 16);
}

// ---------- layer-3 aggregation + log_softmax (F=64, fp32 out) ----------
__global__ __launch_bounds__(256) void k_agg64(const u8* __restrict__ g8,
                                               const u16* __restrict__ g16,
                                               const int* __restrict__ offs,
                                               const int* __restrict__ csr,
                                               const float* __restrict__ dinv,
                                               const float* __restrict__ bias,
                                               float* __restrict__ out, int N) {
    int wid = (blockIdx.x * 256 + threadIdx.x) >> 6;
    if (wid >= N) return;
    int lane = threadIdx.x & 63;
    int s = offs[wid], e = offs[wid + 1];
    float self = bfu2f(((u32)g16[(size_t)wid * 64 + lane]) << 16);
    float a = 0.f;
    int j = s;
    for (; j + 4 <= e; j += 4) {
        int s0 = csr[j], s1 = csr[j + 1], s2 = csr[j + 2], s3 = csr[j + 3];
        u8 b0 = g8[(size_t)s0 * 64 + lane];
        u8 b1 = g8[(size_t)s1 * 64 + lane];
        u8 b2 = g8[(size_t)s2 * 64 + lane];
        u8 b3 = g8[(size_t)s3 * 64 + lane];
        f32x2 d0 = __builtin_amdgcn_cvt_pk_f32_fp8((int)b0, false);
        f32x2 d1 = __builtin_amdgcn_cvt_pk_f32_fp8((int)b1, false);
        f32x2 d2 = __builtin_amdgcn_cvt_pk_f32_fp8((int)b2, false);
        f32x2 d3 = __builtin_amdgcn_cvt_pk_f32_fp8((int)b3, false);
        a += d0.x + d1.x + d2.x + d3.x;
    }
    for (; j < e; j++) {
        f32x2 d0 = __builtin_amdgcn_cvt_pk_f32_fp8((int)g8[(size_t)csr[j] * 64 + lane], false);
        a += d0.x;
    }
    float dv = dinv[wid];
    float v = fmaf(a, dv * 0.0625f, fmaf(self, dv, bias[lane]));
    float m = v;
#pragma unroll
    for (int d = 32; d >= 1; d >>= 1) m = fmaxf(m, __shfl_xor(m, d, 64));
    float ex = __expf(v - m);
    float ssum = ex;
#pragma unroll
    for (int d = 32; d >= 1; d >>= 1) ssum += __shfl_xor(ssum, d, 64);
    out[(size_t)wid * 64 + lane] = v - m - __logf(ssum);
}

extern "C" void kernel_launch(void* const* d_in, const int* in_sizes, int n_in,
                              void* d_out, int out_size, void* d_ws, size_t ws_size,
                              hipStream_t stream) {
    const float* x  = (const float*)d_in[0];
    const int*   ei = (const int*)d_in[1];
    const float* W1 = (const float*)d_in[2];
    const float* b1 = (const float*)d_in[3];
    const float* W2 = (const float*)d_in[4];
    const float* b2 = (const float*)d_in[5];
    const float* W3 = (const float*)d_in[6];
    const float* b3 = (const float*)d_in[7];
    const int N = in_sizes[0] / 128;
    const int E = in_sizes[1] / 2;

    char* ws = (char*)d_ws;
    size_t o = 0;
    auto alloc = [&](size_t bytes) -> char* {
        char* p = ws + o;
        o += (bytes + 255) & ~(size_t)255;
        return p;
    };
    int*   cnt  = (int*)alloc((size_t)N * 4);
    float* dinv = (float*)alloc((size_t)N * 4);
    int*   offs = (int*)alloc((size_t)(N + 1) * 4);
    int*   bsum = (int*)alloc(4096);
    int*   csr  = (int*)alloc((size_t)E * 4);
    u16*   wt1  = (u16*)alloc(128 * 128 * 2);
    u16*   wt2  = (u16*)alloc(128 * 128 * 2);
    u16*   wt3  = (u16*)alloc(64 * 128 * 2);
    u16*   g16  = (u16*)alloc((size_t)N * 128 * 2);
    u8*    g8   = (u8*)alloc((size_t)N * 128);
    u16*   hbuf = (u16*)alloc((size_t)N * 128 * 2);
    int*   pos  = (int*)g16;  // lifetime-disjoint alias: pos dead before first GEMM
    float* outp = (float*)d_out;

    hipMemsetAsync(cnt, 0, (size_t)N * 4, stream);
    int gE = (E + 255) / 256;
    int NB = (N + 1023) / 1024;
    k_count<<<gE, 256, 0, stream>>>(ei, E, cnt, pos);
    k_scan1<<<NB, 256, 0, stream>>>(cnt, N, offs, bsum, dinv);
    k_scan2<<<1, 256, 0, stream>>>(bsum, NB, offs, N);
    k_scan3<<<(N + 255) / 256, 256, 0, stream>>>(offs, bsum, N);
    constexpr int KBIN = 4;
    for (int p = 0; p < KBIN; p++) {
        int lo = (int)((long long)N * p / KBIN);
        int hi = (int)((long long)N * (p + 1) / KBIN);
        k_place<<<gE, 256, 0, stream>>>(ei, pos, E, offs, csr, lo, hi);
    }
    k_wtall<<<(40960 + 255) / 256, 256, 0, stream>>>(W1, W2, W3, wt1, wt2, wt3);

    int gG = (N + 63) / 64;                       // GEMM: 64 nodes/block
    int gA = (int)(((size_t)N * 64 + 255) / 256); // agg: 1 wave/node

    k_gemm<128, true ><<<gG, 256, 0, stream>>>(x,    wt1, dinv, g16, g8, N);
    k_agg128<<<gA, 256, 0, stream>>>(g8, g16, offs, csr, dinv, b1, hbuf, N);
    k_gemm<128, false><<<gG, 256, 0, stream>>>(hbuf, wt2, dinv, g16, g8, N);
    k_agg128<<<gA, 256, 0, stream>>>(g8, g16, offs, csr, dinv, b2, hbuf, N);
    k_gemm<64,  false><<<gG, 256, 0, stream>>>(hbuf, wt3, dinv, g16, g8, N);
    k_agg64<<<gA, 256, 0, stream>>>(g8, g16, offs, csr, dinv, b3, outp, N);
}

// Round 4
// 413.610 us; speedup vs baseline: 1.5135x; 1.1245x over previous
//
#include <hip/hip_runtime.h>

typedef unsigned int u32;
typedef unsigned short u16;
typedef unsigned char u8;
typedef __attribute__((ext_vector_type(8))) short short8;
typedef __attribute__((ext_vector_type(4))) float f32x4;
typedef __attribute__((ext_vector_type(2))) float f32x2;

__device__ inline float bfu2f(u32 u) { return __builtin_bit_cast(float, u); }
__device__ inline u16 f2bf(float f) {
    u32 u = __builtin_bit_cast(u32, f);
    u32 r = (u + 0x7fffu + ((u >> 16) & 1u)) >> 16;  // RTNE
    return (u16)r;
}

// ---------- CSR build ----------
__global__ void k_count(const int* __restrict__ ei, int E, int* __restrict__ cnt,
                        int* __restrict__ pos) {
    int e = blockIdx.x * 256 + threadIdx.x;
    if (e < E) pos[e] = atomicAdd(&cnt[ei[E + e]], 1);
}

__global__ void k_scan1(const int* __restrict__ cnt, int N, int* __restrict__ offs,
                        int* __restrict__ bsum, float* __restrict__ dinv) {
    __shared__ int wsum[4];
    int t = threadIdx.x, b = blockIdx.x;
    int base = b * 1024 + t * 4;
    int4 raw = *(const int4*)(cnt + base);
    int v0 = (base + 0 < N) ? raw.x : 0, v1 = (base + 1 < N) ? raw.y : 0;
    int v2 = (base + 2 < N) ? raw.z : 0, v3 = (base + 3 < N) ? raw.w : 0;
    int s = v0 + v1 + v2 + v3;
    int lane = t & 63, wv = t >> 6;
    int isc = s;
    for (int d = 1; d < 64; d <<= 1) { int o = __shfl_up(isc, d, 64); if (lane >= d) isc += o; }
    if (lane == 63) wsum[wv] = isc;
    __syncthreads();
    int woff = 0;
    for (int w = 0; w < wv; w++) woff += wsum[w];
    int run = woff + isc - s;
    if (base + 0 < N) { offs[base + 0] = run; dinv[base + 0] = rsqrtf((float)(v0 + 1)); } run += v0;
    if (base + 1 < N) { offs[base + 1] = run; dinv[base + 1] = rsqrtf((float)(v1 + 1)); } run += v1;
    if (base + 2 < N) { offs[base + 2] = run; dinv[base + 2] = rsqrtf((float)(v2 + 1)); } run += v2;
    if (base + 3 < N) { offs[base + 3] = run; dinv[base + 3] = rsqrtf((float)(v3 + 1)); }
    if (t == 255) bsum[b] = woff + isc;
}

__global__ void k_scan2(int* __restrict__ bsum, int NB, int* __restrict__ offs, int N) {
    __shared__ int wsum[4];
    int t = threadIdx.x;
    int v = (t < NB) ? bsum[t] : 0;
    int lane = t & 63, wv = t >> 6;
    int isc = v;
    for (int d = 1; d < 64; d <<= 1) { int o = __shfl_up(isc, d, 64); if (lane >= d) isc += o; }
    if (lane == 63) wsum[wv] = isc;
    __syncthreads();
    int woff = 0;
    for (int w = 0; w < wv; w++) woff += wsum[w];
    int incl = woff + isc;
    if (t < NB) bsum[t] = incl - v;
    if (t == 255) offs[N] = incl;
}

__global__ void k_scan3(int* __restrict__ offs, const int* __restrict__ bsum, int N) {
    int i = blockIdx.x * 256 + threadIdx.x;
    if (i < N) offs[i] += bsum[i >> 10];
}

// atomic-free placement, dst-binned so the csr write window stays L2-resident.
__global__ void k_place(const int* __restrict__ ei, const int* __restrict__ pos, int E,
                        const int* __restrict__ offs, int* __restrict__ csr,
                        int lo, int hi) {
    int e = blockIdx.x * 256 + threadIdx.x;
    if (e < E) {
        int dst = ei[E + e];
        if (dst >= lo && dst < hi) csr[offs[dst] + pos[e]] = ei[e];
    }
}

// ---------- fused weight converts (W[K][M] row-major -> Wt[M][K] bf16) ----------
__global__ void k_wtall(const float* __restrict__ W1, const float* __restrict__ W2,
                        const float* __restrict__ W3, u16* __restrict__ wt1,
                        u16* __restrict__ wt2, u16* __restrict__ wt3) {
    int idx = blockIdx.x * 256 + threadIdx.x;
    if (idx < 16384) {
        int k = idx >> 7, m = idx & 127;
        wt1[m * 128 + k] = f2bf(W1[idx]);
    } else if (idx < 32768) {
        int i = idx - 16384, k = i >> 7, m = i & 127;
        wt2[m * 128 + k] = f2bf(W2[i]);
    } else if (idx < 40960) {
        int i = idx - 32768, k = i >> 6, m = i & 63;
        wt3[m * 128 + k] = f2bf(W3[i]);
    }
}

// ---------- GEMM: g = (x @ W) * dinv[row]; writes bf16 (self) + fp8x16 (gather) ----------
template <int M, bool F32IN>
__global__ __launch_bounds__(256) void k_gemm(const void* __restrict__ xin,
                                              const u16* __restrict__ wt,
                                              const float* __restrict__ dinv,
                                              u16* __restrict__ g16,
                                              u8* __restrict__ g8, int N) {
    constexpr int K = 128;
    constexpr int LDK = 136;
    __shared__ u16 lwt[M * LDK];
    int tid = threadIdx.x;
    const uint4* wsrc = (const uint4*)wt;
#pragma unroll
    for (int c = tid; c < M * K / 8; c += 256) {
        int row = c >> 4, kc = c & 15;
        *(uint4*)&lwt[row * LDK + kc * 8] = wsrc[c];
    }
    __syncthreads();
    int lane = tid & 63, wv = tid >> 6;
    int node = blockIdx.x * 64 + wv * 16 + (lane & 15);
    int nodec = min(node, N - 1);
    int kr = (lane >> 4) * 8;
    f32x4 acc[M / 16];
#pragma unroll
    for (int t = 0; t < M / 16; t++) acc[t] = (f32x4){0.f, 0.f, 0.f, 0.f};
#pragma unroll
    for (int ks = 0; ks < 4; ks++) {
        short8 bfr;
        if (F32IN) {
            const float* xr = (const float*)xin + (size_t)nodec * K + ks * 32 + kr;
            float4 fa = *(const float4*)xr;
            float4 fb = *(const float4*)(xr + 4);
            bfr = (short8){(short)f2bf(fa.x), (short)f2bf(fa.y), (short)f2bf(fa.z),
                           (short)f2bf(fa.w), (short)f2bf(fb.x), (short)f2bf(fb.y),
                           (short)f2bf(fb.z), (short)f2bf(fb.w)};
        } else {
            bfr = *(const short8*)((const u16*)xin + (size_t)nodec * K + ks * 32 + kr);
        }
#pragma unroll
        for (int t = 0; t < M / 16; t++) {
            short8 afr = *(const short8*)&lwt[(t * 16 + (lane & 15)) * LDK + ks * 32 + kr];
            acc[t] = __builtin_amdgcn_mfma_f32_16x16x32_bf16(afr, bfr, acc[t], 0, 0, 0);
        }
    }
    if (node < N) {
        float dv = dinv[node];
        float dv16 = dv * 16.0f;
        int r0 = (lane >> 4) * 4;
#pragma unroll
        for (int t = 0; t < M / 16; t++) {
            float v0 = acc[t][0] * dv, v1 = acc[t][1] * dv;
            float v2 = acc[t][2] * dv, v3 = acc[t][3] * dv;
            u32 lo = (u32)f2bf(v0) | ((u32)f2bf(v1) << 16);
            u32 hi = (u32)f2bf(v2) | ((u32)f2bf(v3) << 16);
            *(uint2*)&g16[(size_t)node * M + t * 16 + r0] = make_uint2(lo, hi);
            u32 w = __builtin_amdgcn_cvt_pk_fp8_f32(acc[t][0] * dv16, acc[t][1] * dv16, 0, false);
            w = __builtin_amdgcn_cvt_pk_fp8_f32(acc[t][2] * dv16, acc[t][3] * dv16, w, true);
            *(u32*)(g8 + (size_t)node * M + t * 16 + r0) = w;
        }
    }
}

// ---------- aggregation, quarter-wave edge-parallel ----------
// lanes split 4x16: quarter q handles edge j+q (+j+4+q), lane covers 8 features via uint2 fp8.
__global__ __launch_bounds__(256) void k_agg128(const u8* __restrict__ g8,
                                                const u16* __restrict__ g16,
                                                const int* __restrict__ offs,
                                                const int* __restrict__ csr,
                                                const float* __restrict__ dinv,
                                                const float* __restrict__ bias,
                                                u16* __restrict__ hout, int N) {
    int wid = (blockIdx.x * 256 + threadIdx.x) >> 6;  // one wave per node
    if (wid >= N) return;
    int lane = threadIdx.x & 63;
    int q = lane >> 4;        // edge sub-slot 0..3
    int f = lane & 15;        // feature group: features f*8 .. f*8+7
    int s = offs[wid], e = offs[wid + 1];
    float a[8];
#pragma unroll
    for (int i = 0; i < 8; i++) a[i] = 0.f;
    for (int j = s; j < e; j += 8) {  // 8 edges/iter, 2 gathers in flight per lane
        int iA = j + q, iB = j + 4 + q;
        int srcA = csr[min(iA, e - 1)];
        int srcB = csr[min(iB, e - 1)];
        uint2 wA = *(const uint2*)(g8 + (size_t)srcA * 128 + f * 8);
        uint2 wB = *(const uint2*)(g8 + (size_t)srcB * 128 + f * 8);
        if (iA >= e) { wA.x = 0u; wA.y = 0u; }   // fp8 0x00 == 0.0
        if (iB >= e) { wB.x = 0u; wB.y = 0u; }
        f32x2 p0 = __builtin_amdgcn_cvt_pk_f32_fp8((int)wA.x, false);
        f32x2 p1 = __builtin_amdgcn_cvt_pk_f32_fp8((int)wA.x, true);
        f32x2 p2 = __builtin_amdgcn_cvt_pk_f32_fp8((int)wA.y, false);
        f32x2 p3 = __builtin_amdgcn_cvt_pk_f32_fp8((int)wA.y, true);
        f32x2 r0 = __builtin_amdgcn_cvt_pk_f32_fp8((int)wB.x, false);
        f32x2 r1 = __builtin_amdgcn_cvt_pk_f32_fp8((int)wB.x, true);
        f32x2 r2 = __builtin_amdgcn_cvt_pk_f32_fp8((int)wB.y, false);
        f32x2 r3 = __builtin_amdgcn_cvt_pk_f32_fp8((int)wB.y, true);
        a[0] += p0.x + r0.x; a[1] += p0.y + r0.y;
        a[2] += p1.x + r1.x; a[3] += p1.y + r1.y;
        a[4] += p2.x + r2.x; a[5] += p2.y + r2.y;
        a[6] += p3.x + r3.x; a[7] += p3.y + r3.y;
    }
#pragma unroll
    for (int i = 0; i < 8; i++) {  // merge the 4 quarters
        a[i] += __shfl_xor(a[i], 16, 64);
        a[i] += __shfl_xor(a[i], 32, 64);
    }
    if (lane < 16) {
        float dv = dinv[wid];
        float sc = dv * 0.0625f;
        uint4 sp = *(const uint4*)(g16 + (size_t)wid * 128 + f * 8);  // self, bf16 x8
        float4 b0 = *(const float4*)(bias + f * 8);
        float4 b1 = *(const float4*)(bias + f * 8 + 4);
        float sv[8] = {bfu2f(sp.x << 16), bfu2f(sp.x & 0xffff0000u),
                       bfu2f(sp.y << 16), bfu2f(sp.y & 0xffff0000u),
                       bfu2f(sp.z << 16), bfu2f(sp.z & 0xffff0000u),
                       bfu2f(sp.w << 16), bfu2f(sp.w & 0xffff0000u)};
        float bv[8] = {b0.x, b0.y, b0.z, b0.w, b1.x, b1.y, b1.z, b1.w};
        u32 o[4];
#pragma unroll
        for (int i = 0; i < 4; i++) {
            float v0 = fmaxf(fmaf(a[2 * i], sc, fmaf(sv[2 * i], dv, bv[2 * i])), 0.f);
            float v1 = fmaxf(fmaf(a[2 * i + 1], sc, fmaf(sv[2 * i + 1], dv, bv[2 * i + 1])), 0.f);
            o[i] = (u32)f2bf(v0) | ((u32)f2bf(v1) << 16);
        }
        *(uint4*)&hout[(size_t)wid * 128 + f * 8] = make_uint4(o[0], o[1], o[2], o[3]);
    }
}

// ---------- layer-3 aggregation + log_softmax (F=64, fp32 out) ----------
// quarter q handles edge j+q (+j+4+q); lane covers 4 features via u32 fp8.
__global__ __launch_bounds__(256) void k_agg64(const u8* __restrict__ g8,
                                               const u16* __restrict__ g16,
                                               const int* __restrict__ offs,
                                               const int* __restrict__ csr,
                                               const float* __restrict__ dinv,
                                               const float* __restrict__ bias,
                                               float* __restrict__ out, int N) {
    int wid = (blockIdx.x * 256 + threadIdx.x) >> 6;
    if (wid >= N) return;
    int lane = threadIdx.x & 63;
    int q = lane >> 4;
    int f = lane & 15;  // features f*4 .. f*4+3
    int s = offs[wid], e = offs[wid + 1];
    float a[4] = {0.f, 0.f, 0.f, 0.f};
    for (int j = s; j < e; j += 8) {
        int iA = j + q, iB = j + 4 + q;
        int srcA = csr[min(iA, e - 1)];
        int srcB = csr[min(iB, e - 1)];
        u32 wA = *(const u32*)(g8 + (size_t)srcA * 64 + f * 4);
        u32 wB = *(const u32*)(g8 + (size_t)srcB * 64 + f * 4);
        if (iA >= e) wA = 0u;
        if (iB >= e) wB = 0u;
        f32x2 p0 = __builtin_amdgcn_cvt_pk_f32_fp8((int)wA, false);
        f32x2 p1 = __builtin_amdgcn_cvt_pk_f32_fp8((int)wA, true);
        f32x2 r0 = __builtin_amdgcn_cvt_pk_f32_fp8((int)wB, false);
        f32x2 r1 = __builtin_amdgcn_cvt_pk_f32_fp8((int)wB, true);
        a[0] += p0.x + r0.x; a[1] += p0.y + r0.y;
        a[2] += p1.x + r1.x; a[3] += p1.y + r1.y;
    }
#pragma unroll
    for (int i = 0; i < 4; i++) {
        a[i] += __shfl_xor(a[i], 16, 64);
        a[i] += __shfl_xor(a[i], 32, 64);
    }
    if (lane < 16) {
        float dv = dinv[wid];
        float sc = dv * 0.0625f;
        uint2 sp = *(const uint2*)(g16 + (size_t)wid * 64 + f * 4);  // self, bf16 x4
        float4 bb = *(const float4*)(bias + f * 4);
        float v0 = fmaf(a[0], sc, fmaf(bfu2f(sp.x << 16), dv, bb.x));
        float v1 = fmaf(a[1], sc, fmaf(bfu2f(sp.x & 0xffff0000u), dv, bb.y));
        float v2 = fmaf(a[2], sc, fmaf(bfu2f(sp.y << 16), dv, bb.z));
        float v3 = fmaf(a[3], sc, fmaf(bfu2f(sp.y & 0xffff0000u), dv, bb.w));
        float m = fmaxf(fmaxf(v0, v1), fmaxf(v2, v3));
#pragma unroll
        for (int d = 8; d >= 1; d >>= 1) m = fmaxf(m, __shfl_xor(m, d, 64));
        float ssum = __expf(v0 - m) + __expf(v1 - m) + __expf(v2 - m) + __expf(v3 - m);
#pragma unroll
        for (int d = 8; d >= 1; d >>= 1) ssum += __shfl_xor(ssum, d, 64);
        float lg = m + __logf(ssum);
        *(float4*)&out[(size_t)wid * 64 + f * 4] =
            make_float4(v0 - lg, v1 - lg, v2 - lg, v3 - lg);
    }
}

extern "C" void kernel_launch(void* const* d_in, const int* in_sizes, int n_in,
                              void* d_out, int out_size, void* d_ws, size_t ws_size,
                              hipStream_t stream) {
    const float* x  = (const float*)d_in[0];
    const int*   ei = (const int*)d_in[1];
    const float* W1 = (const float*)d_in[2];
    const float* b1 = (const float*)d_in[3];
    const float* W2 = (const float*)d_in[4];
    const float* b2 = (const float*)d_in[5];
    const float* W3 = (const float*)d_in[6];
    const float* b3 = (const float*)d_in[7];
    const int N = in_sizes[0] / 128;
    const int E = in_sizes[1] / 2;

    char* ws = (char*)d_ws;
    size_t o = 0;
    auto alloc = [&](size_t bytes) -> char* {
        char* p = ws + o;
        o += (bytes + 255) & ~(size_t)255;
        return p;
    };
    int*   cnt  = (int*)alloc((size_t)N * 4);
    float* dinv = (float*)alloc((size_t)N * 4);
    int*   offs = (int*)alloc((size_t)(N + 1) * 4);
    int*   bsum = (int*)alloc(4096);
    int*   csr  = (int*)alloc((size_t)E * 4);
    u16*   wt1  = (u16*)alloc(128 * 128 * 2);
    u16*   wt2  = (u16*)alloc(128 * 128 * 2);
    u16*   wt3  = (u16*)alloc(64 * 128 * 2);
    u16*   g16  = (u16*)alloc((size_t)N * 128 * 2);
    u8*    g8   = (u8*)alloc((size_t)N * 128);
    u16*   hbuf = (u16*)alloc((size_t)N * 128 * 2);
    int*   pos  = (int*)g16;  // lifetime-disjoint alias: pos dead before first GEMM
    float* outp = (float*)d_out;

    hipMemsetAsync(cnt, 0, (size_t)N * 4, stream);
    int gE = (E + 255) / 256;
    int NB = (N + 1023) / 1024;
    k_count<<<gE, 256, 0, stream>>>(ei, E, cnt, pos);
    k_scan1<<<NB, 256, 0, stream>>>(cnt, N, offs, bsum, dinv);
    k_scan2<<<1, 256, 0, stream>>>(bsum, NB, offs, N);
    k_scan3<<<(N + 255) / 256, 256, 0, stream>>>(offs, bsum, N);
    constexpr int KBIN = 4;
    for (int p = 0; p < KBIN; p++) {
        int lo = (int)((long long)N * p / KBIN);
        int hi = (int)((long long)N * (p + 1) / KBIN);
        k_place<<<gE, 256, 0, stream>>>(ei, pos, E, offs, csr, lo, hi);
    }
    k_wtall<<<(40960 + 255) / 256, 256, 0, stream>>>(W1, W2, W3, wt1, wt2, wt3);

    int gG = (N + 63) / 64;                       // GEMM: 64 nodes/block
    int gA = (int)(((size_t)N * 64 + 255) / 256); // agg: 1 wave/node

    k_gemm<128, true ><<<gG, 256, 0, stream>>>(x,    wt1, dinv, g16, g8, N);
    k_agg128<<<gA, 256, 0, stream>>>(g8, g16, offs, csr, dinv, b1, hbuf, N);
    k_gemm<128, false><<<gG, 256, 0, stream>>>(hbuf, wt2, dinv, g16, g8, N);
    k_agg128<<<gA, 256, 0, stream>>>(g8, g16, offs, csr, dinv, b2, hbuf, N);
    k_gemm<64,  false><<<gG, 256, 0, stream>>>(hbuf, wt3, dinv, g16, g8, N);
    k_agg64<<<gA, 256, 0, stream>>>(g8, g16, offs, csr, dinv, b3, outp, N);
}

// Round 5
// 403.851 us; speedup vs baseline: 1.5501x; 1.0242x over previous
//
#include <hip/hip_runtime.h>

typedef unsigned int u32;
typedef unsigned short u16;
typedef unsigned char u8;
typedef __attribute__((ext_vector_type(8))) short short8;
typedef __attribute__((ext_vector_type(4))) float f32x4;
typedef __attribute__((ext_vector_type(2))) float f32x2;

__device__ inline float bfu2f(u32 u) { return __builtin_bit_cast(float, u); }
__device__ inline u16 f2bf(float f) {
    u32 u = __builtin_bit_cast(u32, f);
    u32 r = (u + 0x7fffu + ((u >> 16) & 1u)) >> 16;  // RTNE
    return (u16)r;
}

// ---------- CSR build ----------
// cntP: one counter per 64B line (stride 16 u32) -> far-atomic serialization is
// per-line; padding cuts the serial chain from ~266 (16 dsts/line x deg 17) to ~17.
// key[e] = dst<<8 | pos  (pos = slot within dst's list; max degree << 255 here)
__global__ void k_count(const int* __restrict__ ei, int E, int* __restrict__ cntP,
                        u32* __restrict__ key) {
    int e = blockIdx.x * 256 + threadIdx.x;
    if (e < E) {
        int dst = ei[E + e];
        int p = atomicAdd(&cntP[dst << 4], 1);
        key[e] = ((u32)dst << 8) | (u32)min(p, 255);
    }
}

__global__ void k_scan1(const int* __restrict__ cntP, int N, int* __restrict__ offs,
                        int* __restrict__ bsum, float* __restrict__ dinv) {
    __shared__ int wsum[4];
    int t = threadIdx.x, b = blockIdx.x;
    int base = b * 1024 + t * 4;
    int v0 = (base + 0 < N) ? cntP[(base + 0) << 4] : 0;
    int v1 = (base + 1 < N) ? cntP[(base + 1) << 4] : 0;
    int v2 = (base + 2 < N) ? cntP[(base + 2) << 4] : 0;
    int v3 = (base + 3 < N) ? cntP[(base + 3) << 4] : 0;
    int s = v0 + v1 + v2 + v3;
    int lane = t & 63, wv = t >> 6;
    int isc = s;
    for (int d = 1; d < 64; d <<= 1) { int o = __shfl_up(isc, d, 64); if (lane >= d) isc += o; }
    if (lane == 63) wsum[wv] = isc;
    __syncthreads();
    int woff = 0;
    for (int w = 0; w < wv; w++) woff += wsum[w];
    int run = woff + isc - s;
    if (base + 0 < N) { offs[base + 0] = run; dinv[base + 0] = rsqrtf((float)(v0 + 1)); } run += v0;
    if (base + 1 < N) { offs[base + 1] = run; dinv[base + 1] = rsqrtf((float)(v1 + 1)); } run += v1;
    if (base + 2 < N) { offs[base + 2] = run; dinv[base + 2] = rsqrtf((float)(v2 + 1)); } run += v2;
    if (base + 3 < N) { offs[base + 3] = run; dinv[base + 3] = rsqrtf((float)(v3 + 1)); }
    if (t == 255) bsum[b] = woff + isc;
}

__global__ void k_scan2(int* __restrict__ bsum, int NB, int* __restrict__ offs, int N) {
    __shared__ int wsum[4];
    int t = threadIdx.x;
    int v = (t < NB) ? bsum[t] : 0;
    int lane = t & 63, wv = t >> 6;
    int isc = v;
    for (int d = 1; d < 64; d <<= 1) { int o = __shfl_up(isc, d, 64); if (lane >= d) isc += o; }
    if (lane == 63) wsum[wv] = isc;
    __syncthreads();
    int woff = 0;
    for (int w = 0; w < wv; w++) woff += wsum[w];
    int incl = woff + isc;
    if (t < NB) bsum[t] = incl - v;
    if (t == 255) offs[N] = incl;
}

__global__ void k_scan3(int* __restrict__ offs, const int* __restrict__ bsum, int N) {
    int i = blockIdx.x * 256 + threadIdx.x;
    if (i < N) offs[i] += bsum[i >> 10];
}

// atomic-free placement; 4 dst-bins fused into one dispatch (bin = blockIdx.x/gE,
// blocks dispatch ~in order so each bin's ~1.6MB csr write window stays L2-resident).
__global__ void k_place(const int* __restrict__ ei, const u32* __restrict__ key, int E,
                        const int* __restrict__ offs, int* __restrict__ csr,
                        int gE, int N) {
    int bin = blockIdx.x / gE;
    int e = (blockIdx.x - bin * gE) * 256 + threadIdx.x;
    if (e >= E) return;
    u32 k = key[e];
    int dst = (int)(k >> 8);
    int lo = (int)((long long)N * bin >> 2);
    int hi = (int)((long long)N * (bin + 1) >> 2);
    if (dst >= lo && dst < hi) csr[offs[dst] + (int)(k & 255u)] = ei[e];
}

// ---------- fused weight converts (W[K][M] row-major -> Wt[M][K] bf16) ----------
__global__ void k_wtall(const float* __restrict__ W1, const float* __restrict__ W2,
                        const float* __restrict__ W3, u16* __restrict__ wt1,
                        u16* __restrict__ wt2, u16* __restrict__ wt3) {
    int idx = blockIdx.x * 256 + threadIdx.x;
    if (idx < 16384) {
        int k = idx >> 7, m = idx & 127;
        wt1[m * 128 + k] = f2bf(W1[idx]);
    } else if (idx < 32768) {
        int i = idx - 16384, k = i >> 7, m = i & 127;
        wt2[m * 128 + k] = f2bf(W2[i]);
    } else if (idx < 40960) {
        int i = idx - 32768, k = i >> 6, m = i & 63;
        wt3[m * 128 + k] = f2bf(W3[i]);
    }
}

// ---------- GEMM: g = (x @ W) * dinv[row]; writes bf16 (self) + fp8x16 (gather) ----------
template <int M, bool F32IN>
__global__ __launch_bounds__(256) void k_gemm(const void* __restrict__ xin,
                                              const u16* __restrict__ wt,
                                              const float* __restrict__ dinv,
                                              u16* __restrict__ g16,
                                              u8* __restrict__ g8, int N) {
    constexpr int K = 128;
    constexpr int LDK = 136;
    __shared__ u16 lwt[M * LDK];
    int tid = threadIdx.x;
    const uint4* wsrc = (const uint4*)wt;
#pragma unroll
    for (int c = tid; c < M * K / 8; c += 256) {
        int row = c >> 4, kc = c & 15;
        *(uint4*)&lwt[row * LDK + kc * 8] = wsrc[c];
    }
    __syncthreads();
    int lane = tid & 63, wv = tid >> 6;
    int node = blockIdx.x * 64 + wv * 16 + (lane & 15);
    int nodec = min(node, N - 1);
    int kr = (lane >> 4) * 8;
    f32x4 acc[M / 16];
#pragma unroll
    for (int t = 0; t < M / 16; t++) acc[t] = (f32x4){0.f, 0.f, 0.f, 0.f};
#pragma unroll
    for (int ks = 0; ks < 4; ks++) {
        short8 bfr;
        if (F32IN) {
            const float* xr = (const float*)xin + (size_t)nodec * K + ks * 32 + kr;
            float4 fa = *(const float4*)xr;
            float4 fb = *(const float4*)(xr + 4);
            bfr = (short8){(short)f2bf(fa.x), (short)f2bf(fa.y), (short)f2bf(fa.z),
                           (short)f2bf(fa.w), (short)f2bf(fb.x), (short)f2bf(fb.y),
                           (short)f2bf(fb.z), (short)f2bf(fb.w)};
        } else {
            bfr = *(const short8*)((const u16*)xin + (size_t)nodec * K + ks * 32 + kr);
        }
#pragma unroll
        for (int t = 0; t < M / 16; t++) {
            short8 afr = *(const short8*)&lwt[(t * 16 + (lane & 15)) * LDK + ks * 32 + kr];
            acc[t] = __builtin_amdgcn_mfma_f32_16x16x32_bf16(afr, bfr, acc[t], 0, 0, 0);
        }
    }
    if (node < N) {
        float dv = dinv[node];
        float dv16 = dv * 16.0f;
        int r0 = (lane >> 4) * 4;
#pragma unroll
        for (int t = 0; t < M / 16; t++) {
            float v0 = acc[t][0] * dv, v1 = acc[t][1] * dv;
            float v2 = acc[t][2] * dv, v3 = acc[t][3] * dv;
            u32 lo = (u32)f2bf(v0) | ((u32)f2bf(v1) << 16);
            u32 hi = (u32)f2bf(v2) | ((u32)f2bf(v3) << 16);
            *(uint2*)&g16[(size_t)node * M + t * 16 + r0] = make_uint2(lo, hi);
            u32 w = __builtin_amdgcn_cvt_pk_fp8_f32(acc[t][0] * dv16, acc[t][1] * dv16, 0, false);
            w = __builtin_amdgcn_cvt_pk_fp8_f32(acc[t][2] * dv16, acc[t][3] * dv16, w, true);
            *(u32*)(g8 + (size_t)node * M + t * 16 + r0) = w;
        }
    }
}

// ---------- aggregation, quarter-wave edge-parallel ----------
__global__ __launch_bounds__(256) void k_agg128(const u8* __restrict__ g8,
                                                const u16* __restrict__ g16,
                                                const int* __restrict__ offs,
                                                const int* __restrict__ csr,
                                                const float* __restrict__ dinv,
                                                const float* __restrict__ bias,
                                                u16* __restrict__ hout, int N) {
    int wid = (blockIdx.x * 256 + threadIdx.x) >> 6;  // one wave per node
    if (wid >= N) return;
    int lane = threadIdx.x & 63;
    int q = lane >> 4;
    int f = lane & 15;
    int s = offs[wid], e = offs[wid + 1];
    float a[8];
#pragma unroll
    for (int i = 0; i < 8; i++) a[i] = 0.f;
    for (int j = s; j < e; j += 8) {
        int iA = j + q, iB = j + 4 + q;
        int srcA = csr[min(iA, e - 1)];
        int srcB = csr[min(iB, e - 1)];
        uint2 wA = *(const uint2*)(g8 + (size_t)srcA * 128 + f * 8);
        uint2 wB = *(const uint2*)(g8 + (size_t)srcB * 128 + f * 8);
        if (iA >= e) { wA.x = 0u; wA.y = 0u; }
        if (iB >= e) { wB.x = 0u; wB.y = 0u; }
        f32x2 p0 = __builtin_amdgcn_cvt_pk_f32_fp8((int)wA.x, false);
        f32x2 p1 = __builtin_amdgcn_cvt_pk_f32_fp8((int)wA.x, true);
        f32x2 p2 = __builtin_amdgcn_cvt_pk_f32_fp8((int)wA.y, false);
        f32x2 p3 = __builtin_amdgcn_cvt_pk_f32_fp8((int)wA.y, true);
        f32x2 r0 = __builtin_amdgcn_cvt_pk_f32_fp8((int)wB.x, false);
        f32x2 r1 = __builtin_amdgcn_cvt_pk_f32_fp8((int)wB.x, true);
        f32x2 r2 = __builtin_amdgcn_cvt_pk_f32_fp8((int)wB.y, false);
        f32x2 r3 = __builtin_amdgcn_cvt_pk_f32_fp8((int)wB.y, true);
        a[0] += p0.x + r0.x; a[1] += p0.y + r0.y;
        a[2] += p1.x + r1.x; a[3] += p1.y + r1.y;
        a[4] += p2.x + r2.x; a[5] += p2.y + r2.y;
        a[6] += p3.x + r3.x; a[7] += p3.y + r3.y;
    }
#pragma unroll
    for (int i = 0; i < 8; i++) {
        a[i] += __shfl_xor(a[i], 16, 64);
        a[i] += __shfl_xor(a[i], 32, 64);
    }
    if (lane < 16) {
        float dv = dinv[wid];
        float sc = dv * 0.0625f;
        uint4 sp = *(const uint4*)(g16 + (size_t)wid * 128 + f * 8);
        float4 b0 = *(const float4*)(bias + f * 8);
        float4 b1 = *(const float4*)(bias + f * 8 + 4);
        float sv[8] = {bfu2f(sp.x << 16), bfu2f(sp.x & 0xffff0000u),
                       bfu2f(sp.y << 16), bfu2f(sp.y & 0xffff0000u),
                       bfu2f(sp.z << 16), bfu2f(sp.z & 0xffff0000u),
                       bfu2f(sp.w << 16), bfu2f(sp.w & 0xffff0000u)};
        float bv[8] = {b0.x, b0.y, b0.z, b0.w, b1.x, b1.y, b1.z, b1.w};
        u32 o[4];
#pragma unroll
        for (int i = 0; i < 4; i++) {
            float v0 = fmaxf(fmaf(a[2 * i], sc, fmaf(sv[2 * i], dv, bv[2 * i])), 0.f);
            float v1 = fmaxf(fmaf(a[2 * i + 1], sc, fmaf(sv[2 * i + 1], dv, bv[2 * i + 1])), 0.f);
            o[i] = (u32)f2bf(v0) | ((u32)f2bf(v1) << 16);
        }
        *(uint4*)&hout[(size_t)wid * 128 + f * 8] = make_uint4(o[0], o[1], o[2], o[3]);
    }
}

// ---------- layer-3 aggregation + log_softmax (F=64, fp32 out) ----------
__global__ __launch_bounds__(256) void k_agg64(const u8* __restrict__ g8,
                                               const u16* __restrict__ g16,
                                               const int* __restrict__ offs,
                                               const int* __restrict__ csr,
                                               const float* __restrict__ dinv,
                                               const float* __restrict__ bias,
                                               float* __restrict__ out, int N) {
    int wid = (blockIdx.x * 256 + threadIdx.x) >> 6;
    if (wid >= N) return;
    int lane = threadIdx.x & 63;
    int q = lane >> 4;
    int f = lane & 15;
    int s = offs[wid], e = offs[wid + 1];
    float a[4] = {0.f, 0.f, 0.f, 0.f};
    for (int j = s; j < e; j += 8) {
        int iA = j + q, iB = j + 4 + q;
        int srcA = csr[min(iA, e - 1)];
        int srcB = csr[min(iB, e - 1)];
        u32 wA = *(const u32*)(g8 + (size_t)srcA * 64 + f * 4);
        u32 wB = *(const u32*)(g8 + (size_t)srcB * 64 + f * 4);
        if (iA >= e) wA = 0u;
        if (iB >= e) wB = 0u;
        f32x2 p0 = __builtin_amdgcn_cvt_pk_f32_fp8((int)wA, false);
        f32x2 p1 = __builtin_amdgcn_cvt_pk_f32_fp8((int)wA, true);
        f32x2 r0 = __builtin_amdgcn_cvt_pk_f32_fp8((int)wB, false);
        f32x2 r1 = __builtin_amdgcn_cvt_pk_f32_fp8((int)wB, true);
        a[0] += p0.x + r0.x; a[1] += p0.y + r0.y;
        a[2] += p1.x + r1.x; a[3] += p1.y + r1.y;
    }
#pragma unroll
    for (int i = 0; i < 4; i++) {
        a[i] += __shfl_xor(a[i], 16, 64);
        a[i] += __shfl_xor(a[i], 32, 64);
    }
    if (lane < 16) {
        float dv = dinv[wid];
        float sc = dv * 0.0625f;
        uint2 sp = *(const uint2*)(g16 + (size_t)wid * 64 + f * 4);
        float4 bb = *(const float4*)(bias + f * 4);
        float v0 = fmaf(a[0], sc, fmaf(bfu2f(sp.x << 16), dv, bb.x));
        float v1 = fmaf(a[1], sc, fmaf(bfu2f(sp.x & 0xffff0000u), dv, bb.y));
        float v2 = fmaf(a[2], sc, fmaf(bfu2f(sp.y << 16), dv, bb.z));
        float v3 = fmaf(a[3], sc, fmaf(bfu2f(sp.y & 0xffff0000u), dv, bb.w));
        float m = fmaxf(fmaxf(v0, v1), fmaxf(v2, v3));
#pragma unroll
        for (int d = 8; d >= 1; d >>= 1) m = fmaxf(m, __shfl_xor(m, d, 64));
        float ssum = __expf(v0 - m) + __expf(v1 - m) + __expf(v2 - m) + __expf(v3 - m);
#pragma unroll
        for (int d = 8; d >= 1; d >>= 1) ssum += __shfl_xor(ssum, d, 64);
        float lg = m + __logf(ssum);
        *(float4*)&out[(size_t)wid * 64 + f * 4] =
            make_float4(v0 - lg, v1 - lg, v2 - lg, v3 - lg);
    }
}

extern "C" void kernel_launch(void* const* d_in, const int* in_sizes, int n_in,
                              void* d_out, int out_size, void* d_ws, size_t ws_size,
                              hipStream_t stream) {
    const float* x  = (const float*)d_in[0];
    const int*   ei = (const int*)d_in[1];
    const float* W1 = (const float*)d_in[2];
    const float* b1 = (const float*)d_in[3];
    const float* W2 = (const float*)d_in[4];
    const float* b2 = (const float*)d_in[5];
    const float* W3 = (const float*)d_in[6];
    const float* b3 = (const float*)d_in[7];
    const int N = in_sizes[0] / 128;
    const int E = in_sizes[1] / 2;

    char* ws = (char*)d_ws;
    size_t o = 0;
    auto alloc = [&](size_t bytes) -> char* {
        char* p = ws + o;
        o += (bytes + 255) & ~(size_t)255;
        return p;
    };
    int*   cntP = (int*)alloc((size_t)N * 64);       // 1 counter / 64B line
    float* dinv = (float*)alloc((size_t)N * 4);
    int*   offs = (int*)alloc((size_t)(N + 1) * 4);
    int*   bsum = (int*)alloc(4096);
    int*   csr  = (int*)alloc((size_t)E * 4);
    u16*   wt1  = (u16*)alloc(128 * 128 * 2);
    u16*   wt2  = (u16*)alloc(128 * 128 * 2);
    u16*   wt3  = (u16*)alloc(64 * 128 * 2);
    u16*   g16  = (u16*)alloc((size_t)N * 128 * 2);
    u8*    g8   = (u8*)alloc((size_t)N * 128);
    u16*   hbuf = (u16*)alloc((size_t)N * 128 * 2);
    u32*   key  = (u32*)g16;  // lifetime-disjoint alias: key dead before first GEMM
    float* outp = (float*)d_out;

    hipMemsetAsync(cntP, 0, (size_t)N * 64, stream);
    int gE = (E + 255) / 256;
    int NB = (N + 1023) / 1024;
    k_count<<<gE, 256, 0, stream>>>(ei, E, cntP, key);
    k_scan1<<<NB, 256, 0, stream>>>(cntP, N, offs, bsum, dinv);
    k_scan2<<<1, 256, 0, stream>>>(bsum, NB, offs, N);
    k_scan3<<<(N + 255) / 256, 256, 0, stream>>>(offs, bsum, N);
    k_place<<<4 * gE, 256, 0, stream>>>(ei, key, E, offs, csr, gE, N);
    k_wtall<<<(40960 + 255) / 256, 256, 0, stream>>>(W1, W2, W3, wt1, wt2, wt3);

    int gG = (N + 63) / 64;                       // GEMM: 64 nodes/block
    int gA = (int)(((size_t)N * 64 + 255) / 256); // agg: 1 wave/node

    k_gemm<128, true ><<<gG, 256, 0, stream>>>(x,    wt1, dinv, g16, g8, N);
    k_agg128<<<gA, 256, 0, stream>>>(g8, g16, offs, csr, dinv, b1, hbuf, N);
    k_gemm<128, false><<<gG, 256, 0, stream>>>(hbuf, wt2, dinv, g16, g8, N);
    k_agg128<<<gA, 256, 0, stream>>>(g8, g16, offs, csr, dinv, b2, hbuf, N);
    k_gemm<64,  false><<<gG, 256, 0, stream>>>(hbuf, wt3, dinv, g16, g8, N);
    k_agg64<<<gA, 256, 0, stream>>>(g8, g16, offs, csr, dinv, b3, outp, N);
}

// Round 6
// 362.070 us; speedup vs baseline: 1.7290x; 1.1154x over previous
//
#include <hip/hip_runtime.h>

typedef unsigned int u32;
typedef unsigned short u16;
typedef unsigned char u8;
typedef __attribute__((ext_vector_type(8))) short short8;
typedef __attribute__((ext_vector_type(4))) float f32x4;
typedef __attribute__((ext_vector_type(2))) float f32x2;

#define MAXBIN 1024  // bins of 128 dsts; N=100k -> 782 bins

__device__ inline float bfu2f(u32 u) { return __builtin_bit_cast(float, u); }
__device__ inline u16 f2bf(float f) {
    u32 u = __builtin_bit_cast(u32, f);
    u32 r = (u + 0x7fffu + ((u >> 16) & 1u)) >> 16;  // RTNE
    return (u16)r;
}

// ---------- CSR build: two-level binned counting sort, LDS-resident counters ----
// Far atomics reduced 1.6M -> ~0.4M (memory-side RMW throughput is the wall:
// R5 measured 26e9 atomics/s ~= 845 GB/s of 32B RMW events, padding didn't help).

// per-block LDS histogram of dst>>7, flushed with non-returning global adds
__global__ __launch_bounds__(256) void k_bhist(const int* __restrict__ ei, int E, int W,
                                               int* __restrict__ binTot, int NBIN) {
    __shared__ int h[MAXBIN];
    int tid = threadIdx.x;
    for (int i = tid; i < NBIN; i += 256) h[i] = 0;
    __syncthreads();
    int s = blockIdx.x * W, e = min(E, s + W);
    for (int j = s + tid; j < e; j += 256) atomicAdd(&h[ei[E + j] >> 7], 1);
    __syncthreads();
    for (int i = tid; i < NBIN; i += 256) {
        int v = h[i];
        if (v) atomicAdd(&binTot[i], v);
    }
}

// single-block exclusive scan of bin totals -> binStart, binCur
__global__ void k_bscan(const int* __restrict__ binTot, int NBIN,
                        int* __restrict__ binStart, int* __restrict__ binCur) {
    __shared__ int wsum[4];
    int t = threadIdx.x;
    int base = t * 4;
    int v0 = (base + 0 < NBIN) ? binTot[base + 0] : 0;
    int v1 = (base + 1 < NBIN) ? binTot[base + 1] : 0;
    int v2 = (base + 2 < NBIN) ? binTot[base + 2] : 0;
    int v3 = (base + 3 < NBIN) ? binTot[base + 3] : 0;
    int s = v0 + v1 + v2 + v3;
    int lane = t & 63, wv = t >> 6;
    int isc = s;
    for (int d = 1; d < 64; d <<= 1) { int o = __shfl_up(isc, d, 64); if (lane >= d) isc += o; }
    if (lane == 63) wsum[wv] = isc;
    __syncthreads();
    int woff = 0;
    for (int w = 0; w < wv; w++) woff += wsum[w];
    int run = woff + isc - s;
    if (base + 0 < NBIN) { binStart[base + 0] = run; binCur[base + 0] = run; } run += v0;
    if (base + 1 < NBIN) { binStart[base + 1] = run; binCur[base + 1] = run; } run += v1;
    if (base + 2 < NBIN) { binStart[base + 2] = run; binCur[base + 2] = run; } run += v2;
    if (base + 3 < NBIN) { binStart[base + 3] = run; binCur[base + 3] = run; }
    if (t == 255) binStart[NBIN] = wsum[0] + wsum[1] + wsum[2] + wsum[3];
}

// per-block: LDS count chunk -> one returning atomic per (block,bin) to reserve
// space -> LDS-rank and scatter packed (src<<7 | dst&127) into bin-grouped order
__global__ __launch_bounds__(256) void k_bscatter(const int* __restrict__ ei, int E, int W,
                                                  int* __restrict__ binCur,
                                                  u32* __restrict__ binned, int NBIN) {
    __shared__ int lh[MAXBIN];
    __shared__ int lb[MAXBIN];
    int tid = threadIdx.x;
    for (int i = tid; i < NBIN; i += 256) lh[i] = 0;
    __syncthreads();
    int s = blockIdx.x * W, e = min(E, s + W);
    for (int j = s + tid; j < e; j += 256) atomicAdd(&lh[ei[E + j] >> 7], 1);
    __syncthreads();
    for (int i = tid; i < NBIN; i += 256) {
        int h = lh[i];
        lb[i] = h ? atomicAdd(&binCur[i], h) : 0;
    }
    __syncthreads();
    for (int i = tid; i < NBIN; i += 256) lh[i] = 0;
    __syncthreads();
    for (int j = s + tid; j < e; j += 256) {
        int d = ei[E + j];
        int b = d >> 7;
        int r = atomicAdd(&lh[b], 1);
        binned[lb[b] + r] = ((u32)ei[j] << 7) | (u32)(d & 127);
    }
}

// one block per bin: LDS histogram of 128 dsts -> in-block scan -> offs/dinv/csr
__global__ __launch_bounds__(256) void k_bcsr(const u32* __restrict__ binned,
                                              const int* __restrict__ binStart,
                                              int N, int E, int* __restrict__ offs,
                                              float* __restrict__ dinv,
                                              int* __restrict__ csr, int NBIN) {
    __shared__ int cnt[128];
    __shared__ int off[128];
    __shared__ int tot;
    int b = blockIdx.x;
    int tid = threadIdx.x;
    int dLo = b << 7;
    int nd = min(128, N - dLo);
    int e0 = binStart[b], e1 = binStart[b + 1];
    if (tid < 128) cnt[tid] = 0;
    __syncthreads();
    for (int j = e0 + tid; j < e1; j += 256) atomicAdd(&cnt[binned[j] & 127u], 1);
    __syncthreads();
    int c = (tid < 128) ? cnt[tid] : 0;
    int lane = tid & 63;
    int isc = c;
    for (int d = 1; d < 64; d <<= 1) { int o = __shfl_up(isc, d, 64); if (lane >= d) isc += o; }
    if (tid == 63) tot = isc;
    __syncthreads();
    int add = (tid >= 64 && tid < 128) ? tot : 0;
    if (tid < 128) off[tid] = add + isc - c;
    __syncthreads();
    if (tid < nd) {
        offs[dLo + tid] = e0 + off[tid];
        dinv[dLo + tid] = rsqrtf((float)(c + 1));
    }
    if (b == NBIN - 1 && tid == 0) offs[N] = E;
    if (tid < 128) cnt[tid] = 0;
    __syncthreads();
    for (int j = e0 + tid; j < e1; j += 256) {
        u32 v = binned[j];
        int d7 = (int)(v & 127u);
        int r = atomicAdd(&cnt[d7], 1);
        csr[e0 + off[d7] + r] = (int)(v >> 7);
    }
}

// ---------- fused weight converts (W[K][M] row-major -> Wt[M][K] bf16) ----------
__global__ void k_wtall(const float* __restrict__ W1, const float* __restrict__ W2,
                        const float* __restrict__ W3, u16* __restrict__ wt1,
                        u16* __restrict__ wt2, u16* __restrict__ wt3) {
    int idx = blockIdx.x * 256 + threadIdx.x;
    if (idx < 16384) {
        int k = idx >> 7, m = idx & 127;
        wt1[m * 128 + k] = f2bf(W1[idx]);
    } else if (idx < 32768) {
        int i = idx - 16384, k = i >> 7, m = i & 127;
        wt2[m * 128 + k] = f2bf(W2[i]);
    } else if (idx < 40960) {
        int i = idx - 32768, k = i >> 6, m = i & 63;
        wt3[m * 128 + k] = f2bf(W3[i]);
    }
}

// ---------- GEMM: g = (x @ W) * dinv[row]; writes bf16 (self) + fp8x16 (gather) ----------
template <int M, bool F32IN>
__global__ __launch_bounds__(256) void k_gemm(const void* __restrict__ xin,
                                              const u16* __restrict__ wt,
                                              const float* __restrict__ dinv,
                                              u16* __restrict__ g16,
                                              u8* __restrict__ g8, int N) {
    constexpr int K = 128;
    constexpr int LDK = 136;
    __shared__ u16 lwt[M * LDK];
    int tid = threadIdx.x;
    const uint4* wsrc = (const uint4*)wt;
#pragma unroll
    for (int c = tid; c < M * K / 8; c += 256) {
        int row = c >> 4, kc = c & 15;
        *(uint4*)&lwt[row * LDK + kc * 8] = wsrc[c];
    }
    __syncthreads();
    int lane = tid & 63, wv = tid >> 6;
    int node = blockIdx.x * 64 + wv * 16 + (lane & 15);
    int nodec = min(node, N - 1);
    int kr = (lane >> 4) * 8;
    f32x4 acc[M / 16];
#pragma unroll
    for (int t = 0; t < M / 16; t++) acc[t] = (f32x4){0.f, 0.f, 0.f, 0.f};
#pragma unroll
    for (int ks = 0; ks < 4; ks++) {
        short8 bfr;
        if (F32IN) {
            const float* xr = (const float*)xin + (size_t)nodec * K + ks * 32 + kr;
            float4 fa = *(const float4*)xr;
            float4 fb = *(const float4*)(xr + 4);
            bfr = (short8){(short)f2bf(fa.x), (short)f2bf(fa.y), (short)f2bf(fa.z),
                           (short)f2bf(fa.w), (short)f2bf(fb.x), (short)f2bf(fb.y),
                           (short)f2bf(fb.z), (short)f2bf(fb.w)};
        } else {
            bfr = *(const short8*)((const u16*)xin + (size_t)nodec * K + ks * 32 + kr);
        }
#pragma unroll
        for (int t = 0; t < M / 16; t++) {
            short8 afr = *(const short8*)&lwt[(t * 16 + (lane & 15)) * LDK + ks * 32 + kr];
            acc[t] = __builtin_amdgcn_mfma_f32_16x16x32_bf16(afr, bfr, acc[t], 0, 0, 0);
        }
    }
    if (node < N) {
        float dv = dinv[node];
        float dv16 = dv * 16.0f;
        int r0 = (lane >> 4) * 4;
#pragma unroll
        for (int t = 0; t < M / 16; t++) {
            float v0 = acc[t][0] * dv, v1 = acc[t][1] * dv;
            float v2 = acc[t][2] * dv, v3 = acc[t][3] * dv;
            u32 lo = (u32)f2bf(v0) | ((u32)f2bf(v1) << 16);
            u32 hi = (u32)f2bf(v2) | ((u32)f2bf(v3) << 16);
            *(uint2*)&g16[(size_t)node * M + t * 16 + r0] = make_uint2(lo, hi);
            u32 w = __builtin_amdgcn_cvt_pk_fp8_f32(acc[t][0] * dv16, acc[t][1] * dv16, 0, false);
            w = __builtin_amdgcn_cvt_pk_fp8_f32(acc[t][2] * dv16, acc[t][3] * dv16, w, true);
            *(u32*)(g8 + (size_t)node * M + t * 16 + r0) = w;
        }
    }
}

// ---------- aggregation, quarter-wave edge-parallel ----------
__global__ __launch_bounds__(256) void k_agg128(const u8* __restrict__ g8,
                                                const u16* __restrict__ g16,
                                                const int* __restrict__ offs,
                                                const int* __restrict__ csr,
                                                const float* __restrict__ dinv,
                                                const float* __restrict__ bias,
                                                u16* __restrict__ hout, int N) {
    int wid = (blockIdx.x * 256 + threadIdx.x) >> 6;  // one wave per node
    if (wid >= N) return;
    int lane = threadIdx.x & 63;
    int q = lane >> 4;
    int f = lane & 15;
    int s = offs[wid], e = offs[wid + 1];
    float a[8];
#pragma unroll
    for (int i = 0; i < 8; i++) a[i] = 0.f;
    for (int j = s; j < e; j += 8) {
        int iA = j + q, iB = j + 4 + q;
        int srcA = csr[min(iA, e - 1)];
        int srcB = csr[min(iB, e - 1)];
        uint2 wA = *(const uint2*)(g8 + (size_t)srcA * 128 + f * 8);
        uint2 wB = *(const uint2*)(g8 + (size_t)srcB * 128 + f * 8);
        if (iA >= e) { wA.x = 0u; wA.y = 0u; }
        if (iB >= e) { wB.x = 0u; wB.y = 0u; }
        f32x2 p0 = __builtin_amdgcn_cvt_pk_f32_fp8((int)wA.x, false);
        f32x2 p1 = __builtin_amdgcn_cvt_pk_f32_fp8((int)wA.x, true);
        f32x2 p2 = __builtin_amdgcn_cvt_pk_f32_fp8((int)wA.y, false);
        f32x2 p3 = __builtin_amdgcn_cvt_pk_f32_fp8((int)wA.y, true);
        f32x2 r0 = __builtin_amdgcn_cvt_pk_f32_fp8((int)wB.x, false);
        f32x2 r1 = __builtin_amdgcn_cvt_pk_f32_fp8((int)wB.x, true);
        f32x2 r2 = __builtin_amdgcn_cvt_pk_f32_fp8((int)wB.y, false);
        f32x2 r3 = __builtin_amdgcn_cvt_pk_f32_fp8((int)wB.y, true);
        a[0] += p0.x + r0.x; a[1] += p0.y + r0.y;
        a[2] += p1.x + r1.x; a[3] += p1.y + r1.y;
        a[4] += p2.x + r2.x; a[5] += p2.y + r2.y;
        a[6] += p3.x + r3.x; a[7] += p3.y + r3.y;
    }
#pragma unroll
    for (int i = 0; i < 8; i++) {
        a[i] += __shfl_xor(a[i], 16, 64);
        a[i] += __shfl_xor(a[i], 32, 64);
    }
    if (lane < 16) {
        float dv = dinv[wid];
        float sc = dv * 0.0625f;
        uint4 sp = *(const uint4*)(g16 + (size_t)wid * 128 + f * 8);
        float4 b0 = *(const float4*)(bias + f * 8);
        float4 b1 = *(const float4*)(bias + f * 8 + 4);
        float sv[8] = {bfu2f(sp.x << 16), bfu2f(sp.x & 0xffff0000u),
                       bfu2f(sp.y << 16), bfu2f(sp.y & 0xffff0000u),
                       bfu2f(sp.z << 16), bfu2f(sp.z & 0xffff0000u),
                       bfu2f(sp.w << 16), bfu2f(sp.w & 0xffff0000u)};
        float bv[8] = {b0.x, b0.y, b0.z, b0.w, b1.x, b1.y, b1.z, b1.w};
        u32 o[4];
#pragma unroll
        for (int i = 0; i < 4; i++) {
            float v0 = fmaxf(fmaf(a[2 * i], sc, fmaf(sv[2 * i], dv, bv[2 * i])), 0.f);
            float v1 = fmaxf(fmaf(a[2 * i + 1], sc, fmaf(sv[2 * i + 1], dv, bv[2 * i + 1])), 0.f);
            o[i] = (u32)f2bf(v0) | ((u32)f2bf(v1) << 16);
        }
        *(uint4*)&hout[(size_t)wid * 128 + f * 8] = make_uint4(o[0], o[1], o[2], o[3]);
    }
}

// ---------- layer-3 aggregation + log_softmax (F=64, fp32 out) ----------
__global__ __launch_bounds__(256) void k_agg64(const u8* __restrict__ g8,
                                               const u16* __restrict__ g16,
                                               const int* __restrict__ offs,
                                               const int* __restrict__ csr,
                                               const float* __restrict__ dinv,
                                               const float* __restrict__ bias,
                                               float* __restrict__ out, int N) {
    int wid = (blockIdx.x * 256 + threadIdx.x) >> 6;
    if (wid >= N) return;
    int lane = threadIdx.x & 63;
    int q = lane >> 4;
    int f = lane & 15;
    int s = offs[wid], e = offs[wid + 1];
    float a[4] = {0.f, 0.f, 0.f, 0.f};
    for (int j = s; j < e; j += 8) {
        int iA = j + q, iB = j + 4 + q;
        int srcA = csr[min(iA, e - 1)];
        int srcB = csr[min(iB, e - 1)];
        u32 wA = *(const u32*)(g8 + (size_t)srcA * 64 + f * 4);
        u32 wB = *(const u32*)(g8 + (size_t)srcB * 64 + f * 4);
        if (iA >= e) wA = 0u;
        if (iB >= e) wB = 0u;
        f32x2 p0 = __builtin_amdgcn_cvt_pk_f32_fp8((int)wA, false);
        f32x2 p1 = __builtin_amdgcn_cvt_pk_f32_fp8((int)wA, true);
        f32x2 r0 = __builtin_amdgcn_cvt_pk_f32_fp8((int)wB, false);
        f32x2 r1 = __builtin_amdgcn_cvt_pk_f32_fp8((int)wB, true);
        a[0] += p0.x + r0.x; a[1] += p0.y + r0.y;
        a[2] += p1.x + r1.x; a[3] += p1.y + r1.y;
    }
#pragma unroll
    for (int i = 0; i < 4; i++) {
        a[i] += __shfl_xor(a[i], 16, 64);
        a[i] += __shfl_xor(a[i], 32, 64);
    }
    if (lane < 16) {
        float dv = dinv[wid];
        float sc = dv * 0.0625f;
        uint2 sp = *(const uint2*)(g16 + (size_t)wid * 64 + f * 4);
        float4 bb = *(const float4*)(bias + f * 4);
        float v0 = fmaf(a[0], sc, fmaf(bfu2f(sp.x << 16), dv, bb.x));
        float v1 = fmaf(a[1], sc, fmaf(bfu2f(sp.x & 0xffff0000u), dv, bb.y));
        float v2 = fmaf(a[2], sc, fmaf(bfu2f(sp.y << 16), dv, bb.z));
        float v3 = fmaf(a[3], sc, fmaf(bfu2f(sp.y & 0xffff0000u), dv, bb.w));
        float m = fmaxf(fmaxf(v0, v1), fmaxf(v2, v3));
#pragma unroll
        for (int d = 8; d >= 1; d >>= 1) m = fmaxf(m, __shfl_xor(m, d, 64));
        float ssum = __expf(v0 - m) + __expf(v1 - m) + __expf(v2 - m) + __expf(v3 - m);
#pragma unroll
        for (int d = 8; d >= 1; d >>= 1) ssum += __shfl_xor(ssum, d, 64);
        float lg = m + __logf(ssum);
        *(float4*)&out[(size_t)wid * 64 + f * 4] =
            make_float4(v0 - lg, v1 - lg, v2 - lg, v3 - lg);
    }
}

extern "C" void kernel_launch(void* const* d_in, const int* in_sizes, int n_in,
                              void* d_out, int out_size, void* d_ws, size_t ws_size,
                              hipStream_t stream) {
    const float* x  = (const float*)d_in[0];
    const int*   ei = (const int*)d_in[1];
    const float* W1 = (const float*)d_in[2];
    const float* b1 = (const float*)d_in[3];
    const float* W2 = (const float*)d_in[4];
    const float* b2 = (const float*)d_in[5];
    const float* W3 = (const float*)d_in[6];
    const float* b3 = (const float*)d_in[7];
    const int N = in_sizes[0] / 128;
    const int E = in_sizes[1] / 2;
    const int NBIN = (N + 127) >> 7;  // bins of 128 dsts

    char* ws = (char*)d_ws;
    size_t o = 0;
    auto alloc = [&](size_t bytes) -> char* {
        char* p = ws + o;
        o += (bytes + 255) & ~(size_t)255;
        return p;
    };
    int*   binTot = (int*)alloc((size_t)MAXBIN * 4);
    int*   binSt  = (int*)alloc((size_t)(MAXBIN + 1) * 4);
    int*   binCur = (int*)alloc((size_t)MAXBIN * 4);
    float* dinv   = (float*)alloc((size_t)N * 4);
    int*   offs   = (int*)alloc((size_t)(N + 1) * 4);
    int*   csr    = (int*)alloc((size_t)E * 4);
    u16*   wt1    = (u16*)alloc(128 * 128 * 2);
    u16*   wt2    = (u16*)alloc(128 * 128 * 2);
    u16*   wt3    = (u16*)alloc(64 * 128 * 2);
    u16*   g16    = (u16*)alloc((size_t)N * 128 * 2);
    u8*    g8     = (u8*)alloc((size_t)N * 128);
    u16*   hbuf   = (u16*)alloc((size_t)N * 128 * 2);
    u32*   binned = (u32*)g16;  // lifetime-disjoint alias: dead before first GEMM
    float* outp   = (float*)d_out;

    hipMemsetAsync(binTot, 0, (size_t)MAXBIN * 4, stream);
    int W = (E + 255) / 256;  // edge chunk per block for 256-block passes
    k_bhist<<<256, 256, 0, stream>>>(ei, E, W, binTot, NBIN);
    k_bscan<<<1, 256, 0, stream>>>(binTot, NBIN, binSt, binCur);
    k_bscatter<<<256, 256, 0, stream>>>(ei, E, W, binCur, binned, NBIN);
    k_bcsr<<<NBIN, 256, 0, stream>>>(binned, binSt, N, E, offs, dinv, csr, NBIN);
    k_wtall<<<(40960 + 255) / 256, 256, 0, stream>>>(W1, W2, W3, wt1, wt2, wt3);

    int gG = (N + 63) / 64;                       // GEMM: 64 nodes/block
    int gA = (int)(((size_t)N * 64 + 255) / 256); // agg: 1 wave/node

    k_gemm<128, true ><<<gG, 256, 0, stream>>>(x,    wt1, dinv, g16, g8, N);
    k_agg128<<<gA, 256, 0, stream>>>(g8, g16, offs, csr, dinv, b1, hbuf, N);
    k_gemm<128, false><<<gG, 256, 0, stream>>>(hbuf, wt2, dinv, g16, g8, N);
    k_agg128<<<gA, 256, 0, stream>>>(g8, g16, offs, csr, dinv, b2, hbuf, N);
    k_gemm<64,  false><<<gG, 256, 0, stream>>>(hbuf, wt3, dinv, g16, g8, N);
    k_agg64<<<gA, 256, 0, stream>>>(g8, g16, offs, csr, dinv, b3, outp, N);
}